// Round 4
// baseline (1003.333 us; speedup 1.0000x reference)
//
#include <hip/hip_runtime.h>
#include <hip/hip_bf16.h>
#include <math.h>

#define D_EMBED 512
#define NUM_HEADS 8
#define HEAD_DIM 64
#define D_FF 2048
#define BATCH 2
#define SEQ 4096
#define M_ROWS (BATCH*SEQ)   // 8192

typedef __attribute__((ext_vector_type(8))) short short8;
typedef __attribute__((ext_vector_type(4))) short short4_t;
typedef __attribute__((ext_vector_type(4))) float f32x4;

// Device pass has one of these (R2 run proved it: K16 path taken, LDS=0,
// correctness passed). Host pass may have neither -> benign stub that only
// needs to parse (host never executes device code).
#if __has_builtin(__builtin_amdgcn_mfma_f32_16x16x16bf16_1k)
#define MFMA_K16(a,b,c) __builtin_amdgcn_mfma_f32_16x16x16bf16_1k(a,b,c,0,0,0)
#elif __has_builtin(__builtin_amdgcn_mfma_f32_16x16x16_bf16)
#define MFMA_K16(a,b,c) __builtin_amdgcn_mfma_f32_16x16x16_bf16(a,b,c,0,0,0)
#else
#define MFMA_K16(a,b,c) (c)   // host-pass parse stub
#endif

__device__ inline unsigned short f2b(float f) {
    union { float f; unsigned u; } v; v.f = f;
    unsigned r = v.u + 0x7fffu + ((v.u >> 16) & 1u);
    return (unsigned short)(r >> 16);
}

__device__ inline void gl2lds16(const void* g, void* l) {
    __builtin_amdgcn_global_load_lds(
        (const __attribute__((address_space(1))) unsigned int*)g,
        (__attribute__((address_space(3))) unsigned int*)l, 16, 0, 0);
}

// ---------------------------------------------------------------------------
// GEMM 128x128: C[M][N] = A[M][K](bf16) * BT[N][K](bf16)^T + bias
// EPI 0: bf16; EPI 1: fp32; EPI 2: GELU->bf16. Cols < scale_cols get *0.125.
// ---------------------------------------------------------------------------
template<int EPI>
__global__ __launch_bounds__(256) void gemm_bt(
    const unsigned short* __restrict__ A, const unsigned short* __restrict__ BT,
    const float* __restrict__ bias, void* __restrict__ Cout,
    int M, int N, int K, int scale_cols)
{
    __shared__ __align__(16) unsigned short As[128*32];
    __shared__ __align__(16) unsigned short Bs[128*32];
    const int tid  = threadIdx.x;
    const int wave = tid >> 6, lane = tid & 63;
    const int wy = wave >> 1, wx = wave & 1;
    const int quad = lane >> 4, m16 = lane & 15;
    const int row0 = blockIdx.y * 128, n0 = blockIdx.x * 128;

    f32x4 acc[4][4];
#pragma unroll
    for (int i = 0; i < 4; i++)
#pragma unroll
        for (int j = 0; j < 4; j++) acc[i][j] = (f32x4){0.f,0.f,0.f,0.f};

    const int kIters = K >> 5;
    for (int kt = 0; kt < kIters; ++kt) {
        const int k0 = kt << 5;
#pragma unroll
        for (int it = 0; it < 2; ++it) {
            int g  = it*256 + tid;
            int r  = g >> 2, c8 = (g & 3) << 3;
            gl2lds16(A  + (size_t)(row0 + r)*K + k0 + c8, &As[(size_t)(it*256 + wave*64)*8]);
            gl2lds16(BT + (size_t)(n0  + r)*K + k0 + c8, &Bs[(size_t)(it*256 + wave*64)*8]);
        }
        __syncthreads();
        short8 a[4], b[4];
#pragma unroll
        for (int i = 0; i < 4; i++) a[i] = *(const short8*)&As[(wy*64 + i*16 + m16)*32 + quad*8];
#pragma unroll
        for (int j = 0; j < 4; j++) b[j] = *(const short8*)&Bs[(wx*64 + j*16 + m16)*32 + quad*8];
#pragma unroll
        for (int i = 0; i < 4; i++)
#pragma unroll
            for (int j = 0; j < 4; j++)
                acc[i][j] = __builtin_amdgcn_mfma_f32_16x16x32_bf16(a[i], b[j], acc[i][j], 0, 0, 0);
        __syncthreads();
    }

#pragma unroll
    for (int j = 0; j < 4; j++) {
        int col = n0 + wx*64 + j*16 + m16;
        float bj = bias[col];
        float sc = (col < scale_cols) ? 0.125f : 1.0f;
#pragma unroll
        for (int i = 0; i < 4; i++) {
            int rbase = row0 + wy*64 + i*16 + quad*4;
#pragma unroll
            for (int r = 0; r < 4; r++) {
                float v = (acc[i][j][r] + bj) * sc;
                size_t idx = (size_t)(rbase + r)*N + col;
                if (EPI == 0) {
                    ((unsigned short*)Cout)[idx] = f2b(v);
                } else if (EPI == 1) {
                    ((float*)Cout)[idx] = v;
                } else {
                    float gv = 0.5f * v * (1.0f + erff(v * 0.70710678118654752f));
                    ((unsigned short*)Cout)[idx] = f2b(gv);
                }
            }
        }
    }
}

// ---------------------------------------------------------------------------
// GEMM 64x128 tile (for N=512 matmuls: doubles grid to 512 blocks = 2/CU)
// ---------------------------------------------------------------------------
template<int EPI>
__global__ __launch_bounds__(256) void gemm_bt64(
    const unsigned short* __restrict__ A, const unsigned short* __restrict__ BT,
    const float* __restrict__ bias, void* __restrict__ Cout,
    int M, int N, int K, int scale_cols)
{
    __shared__ __align__(16) unsigned short As[64*32];
    __shared__ __align__(16) unsigned short Bs[128*32];
    const int tid  = threadIdx.x;
    const int wave = tid >> 6, lane = tid & 63;
    const int wy = wave >> 1, wx = wave & 1;
    const int quad = lane >> 4, m16 = lane & 15;
    const int row0 = blockIdx.y * 64, n0 = blockIdx.x * 128;

    f32x4 acc[2][4];
#pragma unroll
    for (int i = 0; i < 2; i++)
#pragma unroll
        for (int j = 0; j < 4; j++) acc[i][j] = (f32x4){0.f,0.f,0.f,0.f};

    const int kIters = K >> 5;
    for (int kt = 0; kt < kIters; ++kt) {
        const int k0 = kt << 5;
        {
            int r = tid >> 2, c8 = (tid & 3) << 3;
            gl2lds16(A + (size_t)(row0 + r)*K + k0 + c8, &As[(size_t)(wave*64)*8]);
        }
#pragma unroll
        for (int it = 0; it < 2; ++it) {
            int g  = it*256 + tid;
            int r  = g >> 2, c8 = (g & 3) << 3;
            gl2lds16(BT + (size_t)(n0 + r)*K + k0 + c8, &Bs[(size_t)(it*256 + wave*64)*8]);
        }
        __syncthreads();
        short8 a[2], b[4];
#pragma unroll
        for (int i = 0; i < 2; i++) a[i] = *(const short8*)&As[(wy*32 + i*16 + m16)*32 + quad*8];
#pragma unroll
        for (int j = 0; j < 4; j++) b[j] = *(const short8*)&Bs[(wx*64 + j*16 + m16)*32 + quad*8];
#pragma unroll
        for (int i = 0; i < 2; i++)
#pragma unroll
            for (int j = 0; j < 4; j++)
                acc[i][j] = __builtin_amdgcn_mfma_f32_16x16x32_bf16(a[i], b[j], acc[i][j], 0, 0, 0);
        __syncthreads();
    }

#pragma unroll
    for (int j = 0; j < 4; j++) {
        int col = n0 + wx*64 + j*16 + m16;
        float bj = bias[col];
        float sc = (col < scale_cols) ? 0.125f : 1.0f;
#pragma unroll
        for (int i = 0; i < 2; i++) {
            int rbase = row0 + wy*32 + i*16 + quad*4;
#pragma unroll
            for (int r = 0; r < 4; r++) {
                float v = (acc[i][j][r] + bj) * sc;
                size_t idx = (size_t)(rbase + r)*N + col;
                if (EPI == 0) {
                    ((unsigned short*)Cout)[idx] = f2b(v);
                } else if (EPI == 1) {
                    ((float*)Cout)[idx] = v;
                } else {
                    float gv = 0.5f * v * (1.0f + erff(v * 0.70710678118654752f));
                    ((unsigned short*)Cout)[idx] = f2b(gv);
                }
            }
        }
    }
}

// ---------------------------------------------------------------------------
// Repack Q,K from fused QKV [8192][1536] into per-head [bh][SEQ][64].
// grid (SEQ/64, 16), 256 threads.
// ---------------------------------------------------------------------------
__global__ __launch_bounds__(256) void repack_qk(
    const unsigned short* __restrict__ QKV,
    unsigned short* __restrict__ Qp, unsigned short* __restrict__ Kp)
{
    const int bh = blockIdx.y, b = bh >> 3, h = bh & 7;
    const int l0 = blockIdx.x * 64;
    const int t = threadIdx.x;
    const int row = t >> 2, c = (t & 3) * 16;
    const unsigned short* src = QKV + (size_t)(b*SEQ + l0 + row)*1536 + h*64 + c;
    const size_t dst = ((size_t)bh*SEQ + l0 + row)*64 + c;
    *(short8*)&Qp[dst]   = *(const short8*)(src);
    *(short8*)&Qp[dst+8] = *(const short8*)(src + 8);
    *(short8*)&Kp[dst]   = *(const short8*)(src + 512);
    *(short8*)&Kp[dst+8] = *(const short8*)(src + 520);
}

// ---------------------------------------------------------------------------
// V (cols 1024..1535 of QKV) -> Vp tiled [bh][SEQ/64][64 d][64 k].
// grid (SEQ/32, 2, 16), block (32,8)
// ---------------------------------------------------------------------------
__global__ void transpose_v(const unsigned short* __restrict__ QKV, unsigned short* __restrict__ VT)
{
    __shared__ unsigned short t[32][33];
    int bh = blockIdx.z, b = bh >> 3, h = bh & 7;
    int l0 = blockIdx.x*32, d0 = blockIdx.y*32;
    int x = threadIdx.x, y = threadIdx.y;
#pragma unroll
    for (int yy = y; yy < 32; yy += 8)
        t[yy][x] = QKV[(size_t)(b*SEQ + l0+yy)*1536 + 1024 + h*64 + d0 + x];
    __syncthreads();
#pragma unroll
    for (int yy = y; yy < 32; yy += 8)
        VT[(((size_t)bh*64 + (l0>>6))*64 + d0+yy)*64 + (l0 & 32) + x] = t[x][yy];
}

// ---------------------------------------------------------------------------
// Flash attention, transposed-score, register-pipelined.
// Qp,Kp: [bh][SEQ][64]; Vp: [bh][SEQ/64][64][64]; O: [B*SEQ][512].
// Per tile: issue V+mask loads and next-K loads BEFORE softmax so they
// overlap QK-MFMA + softmax of the current tile.
// ---------------------------------------------------------------------------
__global__ __launch_bounds__(256) void flash_attn(
    const unsigned short* __restrict__ Qp, const unsigned short* __restrict__ Kp,
    const unsigned short* __restrict__ Vp, const int* __restrict__ mask,
    unsigned short* __restrict__ O)
{
    const int tid = threadIdx.x, wave = tid >> 6, lane = tid & 63;
    const int quad = lane >> 4, m16 = lane & 15;
    const int bh = blockIdx.y, b = bh >> 3, h = bh & 7;
    const int q0 = blockIdx.x * 64 + wave * 16;

    const unsigned short* Qb = Qp + (size_t)bh*SEQ*64;
    const unsigned short* Kb = Kp + (size_t)bh*SEQ*64;
    const unsigned short* Vb = Vp + (size_t)bh*64*4096;
    const int* mbase = mask + b*SEQ;

    short8 qf[2];
    {
        const unsigned short* qp = Qb + (size_t)(q0 + m16)*64 + quad*8;
        qf[0] = *(const short8*)(qp);
        qf[1] = *(const short8*)(qp + 32);
    }

    f32x4 accO[4];
#pragma unroll
    for (int dj = 0; dj < 4; dj++) accO[dj] = (f32x4){0.f,0.f,0.f,0.f};
    float mrun = -1e30f, lrun = 0.f;

    // prologue: K fragments for tile 0
    short8 kf0[4], kf1[4];
#pragma unroll
    for (int nj = 0; nj < 4; nj++) {
        const unsigned short* kp = Kb + (size_t)(nj*16 + m16)*64 + quad*8;
        kf0[nj] = *(const short8*)kp;
        kf1[nj] = *(const short8*)(kp + 32);
    }

    for (int kt = 0; kt < SEQ/64; ++kt) {
        const int key0 = kt * 64;

        // ---- issue independent loads early (current V, current mask, next K)
        const unsigned short* vt = Vb + (size_t)kt*4096;
        short4_t vf[4][4];
#pragma unroll
        for (int nj = 0; nj < 4; nj++)
#pragma unroll
            for (int dj = 0; dj < 4; dj++)
                vf[nj][dj] = *(const short4_t*)(vt + (dj*16 + m16)*64 + nj*16 + quad*4);

        int4 mv[4];
#pragma unroll
        for (int nj = 0; nj < 4; nj++)
            mv[nj] = *(const int4*)(mbase + key0 + nj*16 + quad*4);

        const int keyn = (key0 + 64) & (SEQ - 1);
        short8 kn0[4], kn1[4];
#pragma unroll
        for (int nj = 0; nj < 4; nj++) {
            const unsigned short* kp = Kb + (size_t)(keyn + nj*16 + m16)*64 + quad*8;
            kn0[nj] = *(const short8*)kp;
            kn1[nj] = *(const short8*)(kp + 32);
        }

        // ---- QK^T (S^T: row=key=quad*4+r, col=q=m16); Q pre-scaled by 1/8
        f32x4 st[4];
#pragma unroll
        for (int nj = 0; nj < 4; nj++) {
            f32x4 c = (f32x4){0.f,0.f,0.f,0.f};
            c = __builtin_amdgcn_mfma_f32_16x16x32_bf16(kf0[nj], qf[0], c, 0, 0, 0);
            c = __builtin_amdgcn_mfma_f32_16x16x32_bf16(kf1[nj], qf[1], c, 0, 0, 0);
            st[nj] = c;
        }

        // ---- online softmax (per-lane scores all belong to q=m16)
        float s[4][4];
        float mx = -1e30f;
#pragma unroll
        for (int nj = 0; nj < 4; nj++) {
            s[nj][0] = mv[nj].x ? st[nj][0] : -1e9f;
            s[nj][1] = mv[nj].y ? st[nj][1] : -1e9f;
            s[nj][2] = mv[nj].z ? st[nj][2] : -1e9f;
            s[nj][3] = mv[nj].w ? st[nj][3] : -1e9f;
            mx = fmaxf(mx, fmaxf(fmaxf(s[nj][0], s[nj][1]), fmaxf(s[nj][2], s[nj][3])));
        }
        mx = fmaxf(mx, __shfl_xor(mx, 16, 64));
        mx = fmaxf(mx, __shfl_xor(mx, 32, 64));
        float mnew = fmaxf(mrun, mx);
        float alpha = __expf(mrun - mnew);

        float rs = 0.f;
        float p[4][4];
#pragma unroll
        for (int nj = 0; nj < 4; nj++) {
            p[nj][0] = __expf(s[nj][0] - mnew);
            p[nj][1] = __expf(s[nj][1] - mnew);
            p[nj][2] = __expf(s[nj][2] - mnew);
            p[nj][3] = __expf(s[nj][3] - mnew);
            rs += (p[nj][0] + p[nj][1]) + (p[nj][2] + p[nj][3]);
        }
        rs += __shfl_xor(rs, 16, 64);
        rs += __shfl_xor(rs, 32, 64);
        mrun = mnew;
        lrun = lrun * alpha + rs;

#pragma unroll
        for (int dj = 0; dj < 4; dj++) {
            accO[dj][0] *= alpha; accO[dj][1] *= alpha;
            accO[dj][2] *= alpha; accO[dj][3] *= alpha;
        }

        // ---- PV: O^T += V^T·P^T  (A=V frag, B=P^T in C-layout = K16 B-layout)
        short4_t pb[4];
#pragma unroll
        for (int nj = 0; nj < 4; nj++)
            pb[nj] = (short4_t){(short)f2b(p[nj][0]), (short)f2b(p[nj][1]),
                                (short)f2b(p[nj][2]), (short)f2b(p[nj][3])};
#pragma unroll
        for (int nj = 0; nj < 4; nj++)
#pragma unroll
            for (int dj = 0; dj < 4; dj++)
                accO[dj] = MFMA_K16(vf[nj][dj], pb[nj], accO[dj]);

        // ---- rotate prefetched K
#pragma unroll
        for (int nj = 0; nj < 4; nj++) { kf0[nj] = kn0[nj]; kf1[nj] = kn1[nj]; }
    }

    float rl = 1.0f / lrun;
    // O^T C-layout: row=d=quad*4+r, col=q=m16 -> 4 contiguous bf16 per store
#pragma unroll
    for (int dj = 0; dj < 4; dj++) {
        short4_t o;
        o[0] = (short)f2b(accO[dj][0] * rl);
        o[1] = (short)f2b(accO[dj][1] * rl);
        o[2] = (short)f2b(accO[dj][2] * rl);
        o[3] = (short)f2b(accO[dj][3] * rl);
        *(short4_t*)&O[(size_t)(b*SEQ + q0 + m16)*D_EMBED + h*HEAD_DIM + dj*16 + quad*4] = o;
    }
}

// ---------------------------------------------------------------------------
// y = LayerNorm(A + B)*g + be -> fp32 Yf (and bf16 Yb if non-null)
// ---------------------------------------------------------------------------
__global__ __launch_bounds__(256) void ln_res(
    const float* __restrict__ A, const float* __restrict__ Bv,
    const float* __restrict__ g, const float* __restrict__ be,
    float* __restrict__ Yf, unsigned short* __restrict__ Yb)
{
    const int wave = threadIdx.x >> 6, lane = threadIdx.x & 63;
    const int row = blockIdx.x * 4 + wave;
    const float* ap = A  + (size_t)row*512 + lane*8;
    const float* bp = Bv + (size_t)row*512 + lane*8;
    float v[8]; float s = 0.f;
#pragma unroll
    for (int j = 0; j < 8; j++) { v[j] = ap[j] + bp[j]; s += v[j]; }
#pragma unroll
    for (int off = 32; off >= 1; off >>= 1) s += __shfl_xor(s, off, 64);
    float mu = s * (1.f/512.f);
    float q = 0.f;
#pragma unroll
    for (int j = 0; j < 8; j++) { v[j] -= mu; q += v[j]*v[j]; }
#pragma unroll
    for (int off = 32; off >= 1; off >>= 1) q += __shfl_xor(q, off, 64);
    float rstd = rsqrtf(q * (1.f/512.f) + 1e-5f);
#pragma unroll
    for (int j = 0; j < 8; j++) {
        float y = v[j]*rstd*g[lane*8+j] + be[lane*8+j];
        if (Yf) Yf[(size_t)row*512 + lane*8 + j] = y;
        if (Yb) Yb[(size_t)row*512 + lane*8 + j] = f2b(y);
    }
}

__global__ __launch_bounds__(256) void cvt_f32_bf16(
    const float* __restrict__ X, unsigned short* __restrict__ Y, int n)
{
    int idx = (blockIdx.x * 256 + threadIdx.x) * 4;
    if (idx < n) {
        float4 v = *(const float4*)(X + idx);
        Y[idx+0] = f2b(v.x); Y[idx+1] = f2b(v.y);
        Y[idx+2] = f2b(v.z); Y[idx+3] = f2b(v.w);
    }
}

// W[K][N] fp32 -> WT[N][K] bf16. block (32,8), grid (N/32, K/32)
__global__ void transpose_w(const float* __restrict__ W, unsigned short* __restrict__ WT,
                            int K, int N)
{
    __shared__ float t[32][33];
    int n0 = blockIdx.x*32, k0 = blockIdx.y*32;
    int x = threadIdx.x, y = threadIdx.y;
#pragma unroll
    for (int yy = y; yy < 32; yy += 8) t[yy][x] = W[(size_t)(k0+yy)*N + n0 + x];
    __syncthreads();
#pragma unroll
    for (int yy = y; yy < 32; yy += 8) WT[(size_t)(n0+yy)*K + k0 + x] = f2b(t[x][yy]);
}

__global__ void concat3(const float* __restrict__ a, const float* __restrict__ b,
                        const float* __restrict__ c, float* __restrict__ o)
{
    int i = blockIdx.x*256 + threadIdx.x;  // 1536 total
    o[i] = (i < 512) ? a[i] : ((i < 1024) ? b[i-512] : c[i-1024]);
}

extern "C" void kernel_launch(void* const* d_in, const int* in_sizes, int n_in,
                              void* d_out, int out_size, void* d_ws, size_t ws_size,
                              hipStream_t stream)
{
    const float* x    = (const float*)d_in[0];
    const int*   mask = (const int*)  d_in[1];
    const float* Wq = (const float*)d_in[2];  const float* bq = (const float*)d_in[3];
    const float* Wk = (const float*)d_in[4];  const float* bk = (const float*)d_in[5];
    const float* Wv = (const float*)d_in[6];  const float* bv = (const float*)d_in[7];
    const float* Wo = (const float*)d_in[8];  const float* bo = (const float*)d_in[9];
    const float* ln1g = (const float*)d_in[10]; const float* ln1b = (const float*)d_in[11];
    const float* ln2g = (const float*)d_in[12]; const float* ln2b = (const float*)d_in[13];
    const float* W1 = (const float*)d_in[14]; const float* b1 = (const float*)d_in[15];
    const float* W2 = (const float*)d_in[16]; const float* b2 = (const float*)d_in[17];
    float* out = (float*)d_out;

    char* ws = (char*)d_ws;
    const size_t MB = 1024*1024;
    // liveness-planned map (peak 79 MB):
    unsigned short* xb    = (unsigned short*)(ws + 0);           // 0..8, dead after QKV GEMM
    unsigned short* WqkvT = (unsigned short*)(ws + 8*MB);        // 8..9.5
    unsigned short* W1T   = (unsigned short*)(ws + 10*MB);       // 10..12
    unsigned short* W2T   = (unsigned short*)(ws + 12*MB);       // 12..14
    unsigned short* WoT   = (unsigned short*)(ws + 14*MB);       // 14..14.5
    float*          bqkv  = (float*)(ws + 14*MB + 512*1024);     // 6 KB
    unsigned short* QKVb  = (unsigned short*)(ws + 15*MB);       // 15..39, dead after repack
    unsigned short* Qp    = (unsigned short*)(ws + 39*MB);       // 39..47
    unsigned short* Kp    = (unsigned short*)(ws + 47*MB);       // 47..55
    unsigned short* Vp    = (unsigned short*)(ws + 55*MB);       // 55..63
    unsigned short* ctx   = (unsigned short*)(ws + 63*MB);       // 63..71
    float*          atf   = (float*)(ws + 15*MB);                // 15..31, overlays dead QKVb
    float*          hf    = (float*)(ws + 31*MB);                // 31..47, overlays dead QKVb/Qp
    unsigned short* hb    = (unsigned short*)(ws + 0);           // 0..8, overlays dead xb
    unsigned short* Gb    = (unsigned short*)(ws + 47*MB);       // 47..79, overlays dead Kp/Vp/ctx
    float*          ff    = (float*)(ws + 15*MB);                // 15..31, overlays dead atf

    dim3 tb(32, 8);
    cvt_f32_bf16<<<4096, 256, 0, stream>>>(x, xb, M_ROWS*D_EMBED);
    transpose_w<<<dim3(16,16), tb, 0, stream>>>(Wq, WqkvT,            512, 512);
    transpose_w<<<dim3(16,16), tb, 0, stream>>>(Wk, WqkvT + 512*512,  512, 512);
    transpose_w<<<dim3(16,16), tb, 0, stream>>>(Wv, WqkvT + 1024*512, 512, 512);
    transpose_w<<<dim3(16,16), tb, 0, stream>>>(Wo, WoT, 512, 512);
    transpose_w<<<dim3(64,16), tb, 0, stream>>>(W1, W1T, 512, 2048);
    transpose_w<<<dim3(16,64), tb, 0, stream>>>(W2, W2T, 2048, 512);
    concat3<<<6, 256, 0, stream>>>(bq, bk, bv, bqkv);

    // fused QKV projection, Q pre-scaled by 1/8
    gemm_bt<0><<<dim3(12,64), 256, 0, stream>>>(xb, WqkvT, bqkv, QKVb, M_ROWS, 1536, 512, 512);

    repack_qk<<<dim3(SEQ/64, 16), 256, 0, stream>>>(QKVb, Qp, Kp);
    transpose_v<<<dim3(SEQ/32, 2, 16), tb, 0, stream>>>(QKVb, Vp);
    flash_attn<<<dim3(SEQ/64, 16), 256, 0, stream>>>(Qp, Kp, Vp, mask, ctx);

    gemm_bt64<1><<<dim3(4,128), 256, 0, stream>>>(ctx, WoT, bo, atf, M_ROWS, 512, 512, 0);
    ln_res<<<M_ROWS/4, 256, 0, stream>>>(x, atf, ln1g, ln1b, hf, hb);

    gemm_bt<2><<<dim3(16,64), 256, 0, stream>>>(hb, W1T, b1, Gb, M_ROWS, D_FF, 512, 0);
    gemm_bt64<1><<<dim3(4,128), 256, 0, stream>>>(Gb, W2T, b2, ff, M_ROWS, 512, D_FF, 0);
    ln_res<<<M_ROWS/4, 256, 0, stream>>>(hf, ff, ln2g, ln2b, out, (unsigned short*)nullptr);
}

// Round 5
// 549.869 us; speedup vs baseline: 1.8247x; 1.8247x over previous
//
#include <hip/hip_runtime.h>
#include <hip/hip_bf16.h>
#include <math.h>

#define D_EMBED 512
#define NUM_HEADS 8
#define HEAD_DIM 64
#define D_FF 2048
#define BATCH 2
#define SEQ 4096
#define M_ROWS (BATCH*SEQ)   // 8192

typedef __attribute__((ext_vector_type(8))) short short8;
typedef __attribute__((ext_vector_type(4))) short short4_t;
typedef __attribute__((ext_vector_type(4))) float f32x4;

// Device pass has one of these (R2/R4 runs proved the K16 path is taken and
// correct). Host pass may have neither -> benign parse-only stub.
#if __has_builtin(__builtin_amdgcn_mfma_f32_16x16x16bf16_1k)
#define MFMA_K16(a,b,c) __builtin_amdgcn_mfma_f32_16x16x16bf16_1k(a,b,c,0,0,0)
#elif __has_builtin(__builtin_amdgcn_mfma_f32_16x16x16_bf16)
#define MFMA_K16(a,b,c) __builtin_amdgcn_mfma_f32_16x16x16_bf16(a,b,c,0,0,0)
#else
#define MFMA_K16(a,b,c) (c)   // host-pass parse stub
#endif

__device__ inline unsigned short f2b(float f) {
    union { float f; unsigned u; } v; v.f = f;
    unsigned r = v.u + 0x7fffu + ((v.u >> 16) & 1u);
    return (unsigned short)(r >> 16);
}

__device__ inline void gl2lds16(const void* g, void* l) {
    __builtin_amdgcn_global_load_lds(
        (const __attribute__((address_space(1))) unsigned int*)g,
        (__attribute__((address_space(3))) unsigned int*)l, 16, 0, 0);
}

// ---------------------------------------------------------------------------
// GEMM 128x128: C[M][N] = A[M][K](bf16) * BT[N][K](bf16)^T + bias
// EPI 0: bf16; EPI 1: fp32; EPI 2: GELU->bf16. Cols < scale_cols get *0.125.
// ---------------------------------------------------------------------------
template<int EPI>
__global__ __launch_bounds__(256) void gemm_bt(
    const unsigned short* __restrict__ A, const unsigned short* __restrict__ BT,
    const float* __restrict__ bias, void* __restrict__ Cout,
    int M, int N, int K, int scale_cols)
{
    __shared__ __align__(16) unsigned short As[128*32];
    __shared__ __align__(16) unsigned short Bs[128*32];
    const int tid  = threadIdx.x;
    const int wave = tid >> 6, lane = tid & 63;
    const int wy = wave >> 1, wx = wave & 1;
    const int quad = lane >> 4, m16 = lane & 15;
    const int row0 = blockIdx.y * 128, n0 = blockIdx.x * 128;

    f32x4 acc[4][4];
#pragma unroll
    for (int i = 0; i < 4; i++)
#pragma unroll
        for (int j = 0; j < 4; j++) acc[i][j] = (f32x4){0.f,0.f,0.f,0.f};

    const int kIters = K >> 5;
    for (int kt = 0; kt < kIters; ++kt) {
        const int k0 = kt << 5;
#pragma unroll
        for (int it = 0; it < 2; ++it) {
            int g  = it*256 + tid;
            int r  = g >> 2, c8 = (g & 3) << 3;
            gl2lds16(A  + (size_t)(row0 + r)*K + k0 + c8, &As[(size_t)(it*256 + wave*64)*8]);
            gl2lds16(BT + (size_t)(n0  + r)*K + k0 + c8, &Bs[(size_t)(it*256 + wave*64)*8]);
        }
        __syncthreads();
        short8 a[4], b[4];
#pragma unroll
        for (int i = 0; i < 4; i++) a[i] = *(const short8*)&As[(wy*64 + i*16 + m16)*32 + quad*8];
#pragma unroll
        for (int j = 0; j < 4; j++) b[j] = *(const short8*)&Bs[(wx*64 + j*16 + m16)*32 + quad*8];
#pragma unroll
        for (int i = 0; i < 4; i++)
#pragma unroll
            for (int j = 0; j < 4; j++)
                acc[i][j] = __builtin_amdgcn_mfma_f32_16x16x32_bf16(a[i], b[j], acc[i][j], 0, 0, 0);
        __syncthreads();
    }

#pragma unroll
    for (int j = 0; j < 4; j++) {
        int col = n0 + wx*64 + j*16 + m16;
        float bj = bias[col];
        float sc = (col < scale_cols) ? 0.125f : 1.0f;
#pragma unroll
        for (int i = 0; i < 4; i++) {
            int rbase = row0 + wy*64 + i*16 + quad*4;
#pragma unroll
            for (int r = 0; r < 4; r++) {
                float v = (acc[i][j][r] + bj) * sc;
                size_t idx = (size_t)(rbase + r)*N + col;
                if (EPI == 0) {
                    ((unsigned short*)Cout)[idx] = f2b(v);
                } else if (EPI == 1) {
                    ((float*)Cout)[idx] = v;
                } else {
                    float gv = 0.5f * v * (1.0f + erff(v * 0.70710678118654752f));
                    ((unsigned short*)Cout)[idx] = f2b(gv);
                }
            }
        }
    }
}

// ---------------------------------------------------------------------------
// GEMM 64x128 tile (for N=512 matmuls: doubles grid to 512 blocks = 2/CU)
// ---------------------------------------------------------------------------
template<int EPI>
__global__ __launch_bounds__(256) void gemm_bt64(
    const unsigned short* __restrict__ A, const unsigned short* __restrict__ BT,
    const float* __restrict__ bias, void* __restrict__ Cout,
    int M, int N, int K, int scale_cols)
{
    __shared__ __align__(16) unsigned short As[64*32];
    __shared__ __align__(16) unsigned short Bs[128*32];
    const int tid  = threadIdx.x;
    const int wave = tid >> 6, lane = tid & 63;
    const int wy = wave >> 1, wx = wave & 1;
    const int quad = lane >> 4, m16 = lane & 15;
    const int row0 = blockIdx.y * 64, n0 = blockIdx.x * 128;

    f32x4 acc[2][4];
#pragma unroll
    for (int i = 0; i < 2; i++)
#pragma unroll
        for (int j = 0; j < 4; j++) acc[i][j] = (f32x4){0.f,0.f,0.f,0.f};

    const int kIters = K >> 5;
    for (int kt = 0; kt < kIters; ++kt) {
        const int k0 = kt << 5;
        {
            int r = tid >> 2, c8 = (tid & 3) << 3;
            gl2lds16(A + (size_t)(row0 + r)*K + k0 + c8, &As[(size_t)(wave*64)*8]);
        }
#pragma unroll
        for (int it = 0; it < 2; ++it) {
            int g  = it*256 + tid;
            int r  = g >> 2, c8 = (g & 3) << 3;
            gl2lds16(BT + (size_t)(n0 + r)*K + k0 + c8, &Bs[(size_t)(it*256 + wave*64)*8]);
        }
        __syncthreads();
        short8 a[2], b[4];
#pragma unroll
        for (int i = 0; i < 2; i++) a[i] = *(const short8*)&As[(wy*32 + i*16 + m16)*32 + quad*8];
#pragma unroll
        for (int j = 0; j < 4; j++) b[j] = *(const short8*)&Bs[(wx*64 + j*16 + m16)*32 + quad*8];
#pragma unroll
        for (int i = 0; i < 2; i++)
#pragma unroll
            for (int j = 0; j < 4; j++)
                acc[i][j] = __builtin_amdgcn_mfma_f32_16x16x32_bf16(a[i], b[j], acc[i][j], 0, 0, 0);
        __syncthreads();
    }

#pragma unroll
    for (int j = 0; j < 4; j++) {
        int col = n0 + wx*64 + j*16 + m16;
        float bj = bias[col];
        float sc = (col < scale_cols) ? 0.125f : 1.0f;
#pragma unroll
        for (int i = 0; i < 2; i++) {
            int rbase = row0 + wy*32 + i*16 + quad*4;
#pragma unroll
            for (int r = 0; r < 4; r++) {
                float v = (acc[i][j][r] + bj) * sc;
                size_t idx = (size_t)(rbase + r)*N + col;
                if (EPI == 0) {
                    ((unsigned short*)Cout)[idx] = f2b(v);
                } else if (EPI == 1) {
                    ((float*)Cout)[idx] = v;
                } else {
                    float gv = 0.5f * v * (1.0f + erff(v * 0.70710678118654752f));
                    ((unsigned short*)Cout)[idx] = f2b(gv);
                }
            }
        }
    }
}

// ---------------------------------------------------------------------------
// Repack Q,K from fused QKV [8192][1536] into per-head [bh][SEQ][64].
// grid (SEQ/64, 16), 256 threads.
// ---------------------------------------------------------------------------
__global__ __launch_bounds__(256) void repack_qk(
    const unsigned short* __restrict__ QKV,
    unsigned short* __restrict__ Qp, unsigned short* __restrict__ Kp)
{
    const int bh = blockIdx.y, b = bh >> 3, h = bh & 7;
    const int l0 = blockIdx.x * 64;
    const int t = threadIdx.x;
    const int row = t >> 2, c = (t & 3) * 16;
    const unsigned short* src = QKV + (size_t)(b*SEQ + l0 + row)*1536 + h*64 + c;
    const size_t dst = ((size_t)bh*SEQ + l0 + row)*64 + c;
    *(short8*)&Qp[dst]   = *(const short8*)(src);
    *(short8*)&Qp[dst+8] = *(const short8*)(src + 8);
    *(short8*)&Kp[dst]   = *(const short8*)(src + 512);
    *(short8*)&Kp[dst+8] = *(const short8*)(src + 520);
}

// ---------------------------------------------------------------------------
// V (cols 1024..1535 of QKV) -> VT [bh][64 d][SEQ]. grid (SEQ/32, 2, 16)
// ---------------------------------------------------------------------------
__global__ void transpose_v(const unsigned short* __restrict__ QKV, unsigned short* __restrict__ VT)
{
    __shared__ unsigned short t[32][33];
    int bh = blockIdx.z, b = bh >> 3, h = bh & 7;
    int l0 = blockIdx.x*32, d0 = blockIdx.y*32;
    int x = threadIdx.x, y = threadIdx.y;
#pragma unroll
    for (int yy = y; yy < 32; yy += 8)
        t[yy][x] = QKV[(size_t)(b*SEQ + l0+yy)*1536 + 1024 + h*64 + d0 + x];
    __syncthreads();
#pragma unroll
    for (int yy = y; yy < 32; yy += 8)
        VT[((size_t)bh*64 + d0+yy)*SEQ + l0 + x] = t[x][yy];
}

// ---------------------------------------------------------------------------
// Flash attention, m97-style LDS staging. grid (SEQ/128, B*H), 256 threads.
// Block = 128 q rows; K-tile = 128 keys staged to LDS (shared by all 4 waves).
// Ks: two [128 key][32 d] halves; Vs: four [64 d][32 key] quarters -> 64 B row
// stride = GEMM-proven 2-way (free) bank pattern + global_load_lds contiguity.
// Numerics: verified S^T formulation (softmax per q-column, 2 shuffles) + K16
// PV with P^T already in B-operand layout (no LDS round-trip for P).
// ---------------------------------------------------------------------------
__global__ __launch_bounds__(256) void flash_attn(
    const unsigned short* __restrict__ Qp, const unsigned short* __restrict__ Kp,
    const unsigned short* __restrict__ VT, const int* __restrict__ mask,
    unsigned short* __restrict__ O)
{
    __shared__ __align__(16) unsigned short Ks[2][128*32];
    __shared__ __align__(16) unsigned short Vs[4][64*32];
    const int tid = threadIdx.x, wave = tid >> 6, lane = tid & 63;
    const int quad = lane >> 4, m16 = lane & 15;
    const int bh = blockIdx.y, b = bh >> 3, h = bh & 7;
    const int qbase = blockIdx.x * 128 + wave * 32;

    const unsigned short* Qb = Qp + (size_t)bh*SEQ*64;
    const unsigned short* Kb = Kp + (size_t)bh*SEQ*64;
    const unsigned short* Vb = VT + (size_t)bh*64*SEQ;
    const int* mbase = mask + b*SEQ;

    short8 qf[2][2];
#pragma unroll
    for (int qg = 0; qg < 2; qg++) {
        const unsigned short* qp = Qb + (size_t)(qbase + qg*16 + m16)*64 + quad*8;
        qf[qg][0] = *(const short8*)qp;
        qf[qg][1] = *(const short8*)(qp + 32);
    }

    f32x4 accO[2][4];
#pragma unroll
    for (int qg = 0; qg < 2; qg++)
#pragma unroll
        for (int dj = 0; dj < 4; dj++) accO[qg][dj] = (f32x4){0.f,0.f,0.f,0.f};
    float mrun[2] = {-1e30f, -1e30f}, lrun[2] = {0.f, 0.f};

    for (int kt = 0; kt < SEQ/128; ++kt) {
        const int key0 = kt * 128;
        __syncthreads();   // all waves done reading previous tile
        // stage K tile: two [128][32] halves
#pragma unroll
        for (int it = 0; it < 2; ++it) {
            int g = it*256 + tid;
            int r = g >> 2, c = (g & 3) << 3;
            gl2lds16(Kb + (size_t)(key0 + r)*64 + c,      &Ks[0][(it*256 + wave*64)*8]);
            gl2lds16(Kb + (size_t)(key0 + r)*64 + 32 + c, &Ks[1][(it*256 + wave*64)*8]);
        }
        // stage V^T tile: four [64][32] key-quarters
        {
            int r = tid >> 2, c = (tid & 3) << 3;
#pragma unroll
            for (int qr = 0; qr < 4; ++qr)
                gl2lds16(Vb + (size_t)r*SEQ + key0 + qr*32 + c, &Vs[qr][wave*64*8]);
        }
        // mask (global -> regs, overlaps the barrier drain)
        int4 mv[8];
#pragma unroll
        for (int nj = 0; nj < 8; ++nj)
            mv[nj] = *(const int4*)(mbase + key0 + nj*16 + quad*4);
        __syncthreads();   // staging drained (vmcnt(0) before s_barrier)

        // ---- QK^T: S^T tiles, kf dies immediately per nj
        f32x4 st[2][8];
#pragma unroll
        for (int nj = 0; nj < 8; ++nj) {
            short8 k0 = *(const short8*)&Ks[0][(nj*16 + m16)*32 + quad*8];
            short8 k1 = *(const short8*)&Ks[1][(nj*16 + m16)*32 + quad*8];
#pragma unroll
            for (int qg = 0; qg < 2; ++qg) {
                f32x4 c = (f32x4){0.f,0.f,0.f,0.f};
                c = __builtin_amdgcn_mfma_f32_16x16x32_bf16(k0, qf[qg][0], c, 0, 0, 0);
                c = __builtin_amdgcn_mfma_f32_16x16x32_bf16(k1, qf[qg][1], c, 0, 0, 0);
                st[qg][nj] = c;
            }
        }

        // ---- online softmax per q-group (scores for q=m16 live in-lane)
        short4_t pb[2][8];
#pragma unroll
        for (int qg = 0; qg < 2; ++qg) {
            float s[8][4];
            float mx = -1e30f;
#pragma unroll
            for (int nj = 0; nj < 8; ++nj) {
                s[nj][0] = mv[nj].x ? st[qg][nj][0] : -1e9f;
                s[nj][1] = mv[nj].y ? st[qg][nj][1] : -1e9f;
                s[nj][2] = mv[nj].z ? st[qg][nj][2] : -1e9f;
                s[nj][3] = mv[nj].w ? st[qg][nj][3] : -1e9f;
                mx = fmaxf(mx, fmaxf(fmaxf(s[nj][0], s[nj][1]), fmaxf(s[nj][2], s[nj][3])));
            }
            mx = fmaxf(mx, __shfl_xor(mx, 16, 64));
            mx = fmaxf(mx, __shfl_xor(mx, 32, 64));
            float mnew = fmaxf(mrun[qg], mx);
            float alpha = __expf(mrun[qg] - mnew);
            float rs = 0.f;
#pragma unroll
            for (int nj = 0; nj < 8; ++nj) {
                float p0 = __expf(s[nj][0] - mnew);
                float p1 = __expf(s[nj][1] - mnew);
                float p2 = __expf(s[nj][2] - mnew);
                float p3 = __expf(s[nj][3] - mnew);
                rs += (p0 + p1) + (p2 + p3);
                pb[qg][nj] = (short4_t){(short)f2b(p0), (short)f2b(p1),
                                        (short)f2b(p2), (short)f2b(p3)};
            }
            rs += __shfl_xor(rs, 16, 64);
            rs += __shfl_xor(rs, 32, 64);
            mrun[qg] = mnew;
            lrun[qg] = lrun[qg] * alpha + rs;
#pragma unroll
            for (int dj = 0; dj < 4; ++dj) {
                accO[qg][dj][0] *= alpha; accO[qg][dj][1] *= alpha;
                accO[qg][dj][2] *= alpha; accO[qg][dj][3] *= alpha;
            }
        }

        // ---- PV: O^T += V^T·P^T, V frag shared across both q-groups
#pragma unroll
        for (int nj = 0; nj < 8; ++nj) {
#pragma unroll
            for (int dj = 0; dj < 4; ++dj) {
                short4_t vf = *(const short4_t*)
                    &Vs[nj >> 1][(dj*16 + m16)*32 + (nj & 1)*16 + quad*4];
                accO[0][dj] = MFMA_K16(vf, pb[0][nj], accO[0][dj]);
                accO[1][dj] = MFMA_K16(vf, pb[1][nj], accO[1][dj]);
            }
        }
    }

#pragma unroll
    for (int qg = 0; qg < 2; ++qg) {
        float rl = 1.0f / lrun[qg];
#pragma unroll
        for (int dj = 0; dj < 4; ++dj) {
            short4_t o;
            o[0] = (short)f2b(accO[qg][dj][0] * rl);
            o[1] = (short)f2b(accO[qg][dj][1] * rl);
            o[2] = (short)f2b(accO[qg][dj][2] * rl);
            o[3] = (short)f2b(accO[qg][dj][3] * rl);
            *(short4_t*)&O[(size_t)(b*SEQ + qbase + qg*16 + m16)*D_EMBED
                           + h*HEAD_DIM + dj*16 + quad*4] = o;
        }
    }
}

// ---------------------------------------------------------------------------
// y = LayerNorm(A + B)*g + be -> fp32 Yf (and bf16 Yb if non-null)
// ---------------------------------------------------------------------------
__global__ __launch_bounds__(256) void ln_res(
    const float* __restrict__ A, const float* __restrict__ Bv,
    const float* __restrict__ g, const float* __restrict__ be,
    float* __restrict__ Yf, unsigned short* __restrict__ Yb)
{
    const int wave = threadIdx.x >> 6, lane = threadIdx.x & 63;
    const int row = blockIdx.x * 4 + wave;
    const float* ap = A  + (size_t)row*512 + lane*8;
    const float* bp = Bv + (size_t)row*512 + lane*8;
    float v[8]; float s = 0.f;
#pragma unroll
    for (int j = 0; j < 8; j++) { v[j] = ap[j] + bp[j]; s += v[j]; }
#pragma unroll
    for (int off = 32; off >= 1; off >>= 1) s += __shfl_xor(s, off, 64);
    float mu = s * (1.f/512.f);
    float q = 0.f;
#pragma unroll
    for (int j = 0; j < 8; j++) { v[j] -= mu; q += v[j]*v[j]; }
#pragma unroll
    for (int off = 32; off >= 1; off >>= 1) q += __shfl_xor(q, off, 64);
    float rstd = rsqrtf(q * (1.f/512.f) + 1e-5f);
#pragma unroll
    for (int j = 0; j < 8; j++) {
        float y = v[j]*rstd*g[lane*8+j] + be[lane*8+j];
        if (Yf) Yf[(size_t)row*512 + lane*8 + j] = y;
        if (Yb) Yb[(size_t)row*512 + lane*8 + j] = f2b(y);
    }
}

__global__ __launch_bounds__(256) void cvt_f32_bf16(
    const float* __restrict__ X, unsigned short* __restrict__ Y, int n)
{
    int idx = (blockIdx.x * 256 + threadIdx.x) * 4;
    if (idx < n) {
        float4 v = *(const float4*)(X + idx);
        Y[idx+0] = f2b(v.x); Y[idx+1] = f2b(v.y);
        Y[idx+2] = f2b(v.z); Y[idx+3] = f2b(v.w);
    }
}

// W[K][N] fp32 -> WT[N][K] bf16. block (32,8), grid (N/32, K/32)
__global__ void transpose_w(const float* __restrict__ W, unsigned short* __restrict__ WT,
                            int K, int N)
{
    __shared__ float t[32][33];
    int n0 = blockIdx.x*32, k0 = blockIdx.y*32;
    int x = threadIdx.x, y = threadIdx.y;
#pragma unroll
    for (int yy = y; yy < 32; yy += 8) t[yy][x] = W[(size_t)(k0+yy)*N + n0 + x];
    __syncthreads();
#pragma unroll
    for (int yy = y; yy < 32; yy += 8) WT[(size_t)(n0+yy)*K + k0 + x] = f2b(t[x][yy]);
}

__global__ void concat3(const float* __restrict__ a, const float* __restrict__ b,
                        const float* __restrict__ c, float* __restrict__ o)
{
    int i = blockIdx.x*256 + threadIdx.x;  // 1536 total
    o[i] = (i < 512) ? a[i] : ((i < 1024) ? b[i-512] : c[i-1024]);
}

extern "C" void kernel_launch(void* const* d_in, const int* in_sizes, int n_in,
                              void* d_out, int out_size, void* d_ws, size_t ws_size,
                              hipStream_t stream)
{
    const float* x    = (const float*)d_in[0];
    const int*   mask = (const int*)  d_in[1];
    const float* Wq = (const float*)d_in[2];  const float* bq = (const float*)d_in[3];
    const float* Wk = (const float*)d_in[4];  const float* bk = (const float*)d_in[5];
    const float* Wv = (const float*)d_in[6];  const float* bv = (const float*)d_in[7];
    const float* Wo = (const float*)d_in[8];  const float* bo = (const float*)d_in[9];
    const float* ln1g = (const float*)d_in[10]; const float* ln1b = (const float*)d_in[11];
    const float* ln2g = (const float*)d_in[12]; const float* ln2b = (const float*)d_in[13];
    const float* W1 = (const float*)d_in[14]; const float* b1 = (const float*)d_in[15];
    const float* W2 = (const float*)d_in[16]; const float* b2 = (const float*)d_in[17];
    float* out = (float*)d_out;

    char* ws = (char*)d_ws;
    const size_t MB = 1024*1024;
    // liveness-planned map (peak 79 MB):
    unsigned short* xb    = (unsigned short*)(ws + 0);           // 0..8, dead after QKV GEMM
    unsigned short* WqkvT = (unsigned short*)(ws + 8*MB);        // 8..9.5
    unsigned short* W1T   = (unsigned short*)(ws + 10*MB);       // 10..12
    unsigned short* W2T   = (unsigned short*)(ws + 12*MB);       // 12..14
    unsigned short* WoT   = (unsigned short*)(ws + 14*MB);       // 14..14.5
    float*          bqkv  = (float*)(ws + 14*MB + 512*1024);     // 6 KB
    unsigned short* QKVb  = (unsigned short*)(ws + 15*MB);       // 15..39, dead after repack
    unsigned short* Qp    = (unsigned short*)(ws + 39*MB);       // 39..47
    unsigned short* Kp    = (unsigned short*)(ws + 47*MB);       // 47..55
    unsigned short* Vp    = (unsigned short*)(ws + 55*MB);       // 55..63
    unsigned short* ctx   = (unsigned short*)(ws + 63*MB);       // 63..71
    float*          atf   = (float*)(ws + 15*MB);                // 15..31, overlays dead QKVb
    float*          hf    = (float*)(ws + 31*MB);                // 31..47, overlays dead QKVb/Qp
    unsigned short* hb    = (unsigned short*)(ws + 0);           // 0..8, overlays dead xb
    unsigned short* Gb    = (unsigned short*)(ws + 47*MB);       // 47..79, overlays dead Kp/Vp/ctx
    float*          ff    = (float*)(ws + 15*MB);                // 15..31, overlays dead atf

    dim3 tb(32, 8);
    cvt_f32_bf16<<<4096, 256, 0, stream>>>(x, xb, M_ROWS*D_EMBED);
    transpose_w<<<dim3(16,16), tb, 0, stream>>>(Wq, WqkvT,            512, 512);
    transpose_w<<<dim3(16,16), tb, 0, stream>>>(Wk, WqkvT + 512*512,  512, 512);
    transpose_w<<<dim3(16,16), tb, 0, stream>>>(Wv, WqkvT + 1024*512, 512, 512);
    transpose_w<<<dim3(16,16), tb, 0, stream>>>(Wo, WoT, 512, 512);
    transpose_w<<<dim3(64,16), tb, 0, stream>>>(W1, W1T, 512, 2048);
    transpose_w<<<dim3(16,64), tb, 0, stream>>>(W2, W2T, 2048, 512);
    concat3<<<6, 256, 0, stream>>>(bq, bk, bv, bqkv);

    // fused QKV projection, Q pre-scaled by 1/8
    gemm_bt<0><<<dim3(12,64), 256, 0, stream>>>(xb, WqkvT, bqkv, QKVb, M_ROWS, 1536, 512, 512);

    repack_qk<<<dim3(SEQ/64, 16), 256, 0, stream>>>(QKVb, Qp, Kp);
    transpose_v<<<dim3(SEQ/32, 2, 16), tb, 0, stream>>>(QKVb, Vp);
    flash_attn<<<dim3(SEQ/128, 16), 256, 0, stream>>>(Qp, Kp, Vp, mask, ctx);

    gemm_bt64<1><<<dim3(4,128), 256, 0, stream>>>(ctx, WoT, bo, atf, M_ROWS, 512, 512, 0);
    ln_res<<<M_ROWS/4, 256, 0, stream>>>(x, atf, ln1g, ln1b, hf, hb);

    gemm_bt<2><<<dim3(16,64), 256, 0, stream>>>(hb, W1T, b1, Gb, M_ROWS, D_FF, 512, 0);
    gemm_bt64<1><<<dim3(4,128), 256, 0, stream>>>(Gb, W2T, b2, ff, M_ROWS, 512, D_FF, 0);
    ln_res<<<M_ROWS/4, 256, 0, stream>>>(hf, ff, ln2g, ln2b, out, (unsigned short*)nullptr);
}

// Round 6
// 499.546 us; speedup vs baseline: 2.0085x; 1.1007x over previous
//
#include <hip/hip_runtime.h>
#include <hip/hip_bf16.h>
#include <math.h>

#define D_EMBED 512
#define NUM_HEADS 8
#define HEAD_DIM 64
#define D_FF 2048
#define BATCH 2
#define SEQ 4096
#define M_ROWS (BATCH*SEQ)   // 8192

typedef __attribute__((ext_vector_type(8))) short short8;
typedef __attribute__((ext_vector_type(4))) short short4_t;
typedef __attribute__((ext_vector_type(4))) float f32x4;

// Device pass has one of these (R2/R4/R5 runs proved the K16 path is taken and
// correct). Host pass may have neither -> benign parse-only stub.
#if __has_builtin(__builtin_amdgcn_mfma_f32_16x16x16bf16_1k)
#define MFMA_K16(a,b,c) __builtin_amdgcn_mfma_f32_16x16x16bf16_1k(a,b,c,0,0,0)
#elif __has_builtin(__builtin_amdgcn_mfma_f32_16x16x16_bf16)
#define MFMA_K16(a,b,c) __builtin_amdgcn_mfma_f32_16x16x16_bf16(a,b,c,0,0,0)
#else
#define MFMA_K16(a,b,c) (c)   // host-pass parse stub
#endif

__device__ inline unsigned short f2b(float f) {
    union { float f; unsigned u; } v; v.f = f;
    unsigned r = v.u + 0x7fffu + ((v.u >> 16) & 1u);
    return (unsigned short)(r >> 16);
}

__device__ inline void gl2lds16(const void* g, void* l) {
    __builtin_amdgcn_global_load_lds(
        (const __attribute__((address_space(1))) unsigned int*)g,
        (__attribute__((address_space(3))) unsigned int*)l, 16, 0, 0);
}

// XOR swizzle: 64B LDS rows, 4 chunks of 16B. chunk' = chunk ^ ((row>>1)&3).
// Staging permutes the SOURCE chunk (same 64B cacheline -> coalescing kept);
// readers XOR their chunk index identically. Turns the 8-lanes-per-4-banks
// aliasing (8-way) into full 32-bank coverage (2-way = free).

// ---------------------------------------------------------------------------
// GEMM 128x128: C[M][N] = A[M][K](bf16) * BT[N][K](bf16)^T + bias
// EPI 0: bf16; EPI 1: fp32; EPI 2: GELU->bf16. Cols < scale_cols get *0.125.
// ---------------------------------------------------------------------------
template<int EPI>
__global__ __launch_bounds__(256) void gemm_bt(
    const unsigned short* __restrict__ A, const unsigned short* __restrict__ BT,
    const float* __restrict__ bias, void* __restrict__ Cout,
    int M, int N, int K, int scale_cols)
{
    __shared__ __align__(16) unsigned short As[128*32];
    __shared__ __align__(16) unsigned short Bs[128*32];
    const int tid  = threadIdx.x;
    const int wave = tid >> 6, lane = tid & 63;
    const int wy = wave >> 1, wx = wave & 1;
    const int quad = lane >> 4, m16 = lane & 15;
    const int row0 = blockIdx.y * 128, n0 = blockIdx.x * 128;
    const int rdoff = (quad ^ ((m16 >> 1) & 3)) * 8;   // swizzled read chunk

    f32x4 acc[4][4];
#pragma unroll
    for (int i = 0; i < 4; i++)
#pragma unroll
        for (int j = 0; j < 4; j++) acc[i][j] = (f32x4){0.f,0.f,0.f,0.f};

    const int kIters = K >> 5;
    for (int kt = 0; kt < kIters; ++kt) {
        const int k0 = kt << 5;
#pragma unroll
        for (int it = 0; it < 2; ++it) {
            int g  = it*256 + tid;
            int r  = g >> 2;
            int c8 = (((g & 3) ^ ((g >> 3) & 3)) << 3);   // swizzled source chunk
            gl2lds16(A  + (size_t)(row0 + r)*K + k0 + c8, &As[(size_t)(it*256 + wave*64)*8]);
            gl2lds16(BT + (size_t)(n0  + r)*K + k0 + c8, &Bs[(size_t)(it*256 + wave*64)*8]);
        }
        __syncthreads();
        short8 a[4], b[4];
#pragma unroll
        for (int i = 0; i < 4; i++) a[i] = *(const short8*)&As[(wy*64 + i*16 + m16)*32 + rdoff];
#pragma unroll
        for (int j = 0; j < 4; j++) b[j] = *(const short8*)&Bs[(wx*64 + j*16 + m16)*32 + rdoff];
#pragma unroll
        for (int i = 0; i < 4; i++)
#pragma unroll
            for (int j = 0; j < 4; j++)
                acc[i][j] = __builtin_amdgcn_mfma_f32_16x16x32_bf16(a[i], b[j], acc[i][j], 0, 0, 0);
        __syncthreads();
    }

#pragma unroll
    for (int j = 0; j < 4; j++) {
        int col = n0 + wx*64 + j*16 + m16;
        float bj = bias[col];
        float sc = (col < scale_cols) ? 0.125f : 1.0f;
#pragma unroll
        for (int i = 0; i < 4; i++) {
            int rbase = row0 + wy*64 + i*16 + quad*4;
#pragma unroll
            for (int r = 0; r < 4; r++) {
                float v = (acc[i][j][r] + bj) * sc;
                size_t idx = (size_t)(rbase + r)*N + col;
                if (EPI == 0) {
                    ((unsigned short*)Cout)[idx] = f2b(v);
                } else if (EPI == 1) {
                    ((float*)Cout)[idx] = v;
                } else {
                    float gv = 0.5f * v * (1.0f + erff(v * 0.70710678118654752f));
                    ((unsigned short*)Cout)[idx] = f2b(gv);
                }
            }
        }
    }
}

// ---------------------------------------------------------------------------
// GEMM 64x128 tile (for N=512 matmuls: doubles grid to 512 blocks = 2/CU)
// ---------------------------------------------------------------------------
template<int EPI>
__global__ __launch_bounds__(256) void gemm_bt64(
    const unsigned short* __restrict__ A, const unsigned short* __restrict__ BT,
    const float* __restrict__ bias, void* __restrict__ Cout,
    int M, int N, int K, int scale_cols)
{
    __shared__ __align__(16) unsigned short As[64*32];
    __shared__ __align__(16) unsigned short Bs[128*32];
    const int tid  = threadIdx.x;
    const int wave = tid >> 6, lane = tid & 63;
    const int wy = wave >> 1, wx = wave & 1;
    const int quad = lane >> 4, m16 = lane & 15;
    const int row0 = blockIdx.y * 64, n0 = blockIdx.x * 128;
    const int rdoff = (quad ^ ((m16 >> 1) & 3)) * 8;

    f32x4 acc[2][4];
#pragma unroll
    for (int i = 0; i < 2; i++)
#pragma unroll
        for (int j = 0; j < 4; j++) acc[i][j] = (f32x4){0.f,0.f,0.f,0.f};

    const int kIters = K >> 5;
    for (int kt = 0; kt < kIters; ++kt) {
        const int k0 = kt << 5;
        {
            int r = tid >> 2;
            int c8 = (((tid & 3) ^ ((tid >> 3) & 3)) << 3);
            gl2lds16(A + (size_t)(row0 + r)*K + k0 + c8, &As[(size_t)(wave*64)*8]);
        }
#pragma unroll
        for (int it = 0; it < 2; ++it) {
            int g  = it*256 + tid;
            int r  = g >> 2;
            int c8 = (((g & 3) ^ ((g >> 3) & 3)) << 3);
            gl2lds16(BT + (size_t)(n0 + r)*K + k0 + c8, &Bs[(size_t)(it*256 + wave*64)*8]);
        }
        __syncthreads();
        short8 a[2], b[4];
#pragma unroll
        for (int i = 0; i < 2; i++) a[i] = *(const short8*)&As[(wy*32 + i*16 + m16)*32 + rdoff];
#pragma unroll
        for (int j = 0; j < 4; j++) b[j] = *(const short8*)&Bs[(wx*64 + j*16 + m16)*32 + rdoff];
#pragma unroll
        for (int i = 0; i < 2; i++)
#pragma unroll
            for (int j = 0; j < 4; j++)
                acc[i][j] = __builtin_amdgcn_mfma_f32_16x16x32_bf16(a[i], b[j], acc[i][j], 0, 0, 0);
        __syncthreads();
    }

#pragma unroll
    for (int j = 0; j < 4; j++) {
        int col = n0 + wx*64 + j*16 + m16;
        float bj = bias[col];
        float sc = (col < scale_cols) ? 0.125f : 1.0f;
#pragma unroll
        for (int i = 0; i < 2; i++) {
            int rbase = row0 + wy*32 + i*16 + quad*4;
#pragma unroll
            for (int r = 0; r < 4; r++) {
                float v = (acc[i][j][r] + bj) * sc;
                size_t idx = (size_t)(rbase + r)*N + col;
                if (EPI == 0) {
                    ((unsigned short*)Cout)[idx] = f2b(v);
                } else if (EPI == 1) {
                    ((float*)Cout)[idx] = v;
                } else {
                    float gv = 0.5f * v * (1.0f + erff(v * 0.70710678118654752f));
                    ((unsigned short*)Cout)[idx] = f2b(gv);
                }
            }
        }
    }
}

// ---------------------------------------------------------------------------
// Repack Q,K from fused QKV [8192][1536] into per-head [bh][SEQ][64].
// grid (SEQ/64, 16), 256 threads.
// ---------------------------------------------------------------------------
__global__ __launch_bounds__(256) void repack_qk(
    const unsigned short* __restrict__ QKV,
    unsigned short* __restrict__ Qp, unsigned short* __restrict__ Kp)
{
    const int bh = blockIdx.y, b = bh >> 3, h = bh & 7;
    const int l0 = blockIdx.x * 64;
    const int t = threadIdx.x;
    const int row = t >> 2, c = (t & 3) * 16;
    const unsigned short* src = QKV + (size_t)(b*SEQ + l0 + row)*1536 + h*64 + c;
    const size_t dst = ((size_t)bh*SEQ + l0 + row)*64 + c;
    *(short8*)&Qp[dst]   = *(const short8*)(src);
    *(short8*)&Qp[dst+8] = *(const short8*)(src + 8);
    *(short8*)&Kp[dst]   = *(const short8*)(src + 512);
    *(short8*)&Kp[dst+8] = *(const short8*)(src + 520);
}

// ---------------------------------------------------------------------------
// V (cols 1024..1535 of QKV) -> VT [bh][64 d][SEQ]. grid (SEQ/32, 2, 16)
// ---------------------------------------------------------------------------
__global__ void transpose_v(const unsigned short* __restrict__ QKV, unsigned short* __restrict__ VT)
{
    __shared__ unsigned short t[32][33];
    int bh = blockIdx.z, b = bh >> 3, h = bh & 7;
    int l0 = blockIdx.x*32, d0 = blockIdx.y*32;
    int x = threadIdx.x, y = threadIdx.y;
#pragma unroll
    for (int yy = y; yy < 32; yy += 8)
        t[yy][x] = QKV[(size_t)(b*SEQ + l0+yy)*1536 + 1024 + h*64 + d0 + x];
    __syncthreads();
#pragma unroll
    for (int yy = y; yy < 32; yy += 8)
        VT[((size_t)bh*64 + d0+yy)*SEQ + l0 + x] = t[x][yy];
}

// ---------------------------------------------------------------------------
// Flash attention, m97-style LDS staging + XOR bank swizzle.
// grid (SEQ/128, B*H), 256 threads. Block = 128 q rows; K-tile = 128 keys.
// ---------------------------------------------------------------------------
__global__ __launch_bounds__(256) void flash_attn(
    const unsigned short* __restrict__ Qp, const unsigned short* __restrict__ Kp,
    const unsigned short* __restrict__ VT, const int* __restrict__ mask,
    unsigned short* __restrict__ O)
{
    __shared__ __align__(16) unsigned short Ks[2][128*32];
    __shared__ __align__(16) unsigned short Vs[4][64*32];
    const int tid = threadIdx.x, wave = tid >> 6, lane = tid & 63;
    const int quad = lane >> 4, m16 = lane & 15;
    const int bh = blockIdx.y, b = bh >> 3, h = bh & 7;
    const int qbase = blockIdx.x * 128 + wave * 32;
    const int fsw = (m16 >> 1) & 3;                  // row-derived swizzle key
    const int koff = (quad ^ fsw) * 8;               // Ks b128 read offset
    const int vch  = (quad >> 1);                    // Vs chunk base
    const int vsub = (quad & 1) * 4;                 // Vs 8B sub-offset

    const unsigned short* Qb = Qp + (size_t)bh*SEQ*64;
    const unsigned short* Kb = Kp + (size_t)bh*SEQ*64;
    const unsigned short* Vb = VT + (size_t)bh*64*SEQ;
    const int* mbase = mask + b*SEQ;

    short8 qf[2][2];
#pragma unroll
    for (int qg = 0; qg < 2; qg++) {
        const unsigned short* qp = Qb + (size_t)(qbase + qg*16 + m16)*64 + quad*8;
        qf[qg][0] = *(const short8*)qp;
        qf[qg][1] = *(const short8*)(qp + 32);
    }

    f32x4 accO[2][4];
#pragma unroll
    for (int qg = 0; qg < 2; qg++)
#pragma unroll
        for (int dj = 0; dj < 4; dj++) accO[qg][dj] = (f32x4){0.f,0.f,0.f,0.f};
    float mrun[2] = {-1e30f, -1e30f}, lrun[2] = {0.f, 0.f};

    for (int kt = 0; kt < SEQ/128; ++kt) {
        const int key0 = kt * 128;
        __syncthreads();   // all waves done reading previous tile
        // stage K tile: two [128][32] halves, source-chunk swizzled
#pragma unroll
        for (int it = 0; it < 2; ++it) {
            int g = it*256 + tid;
            int r = g >> 2;
            int c8 = (((g & 3) ^ ((g >> 3) & 3)) << 3);
            gl2lds16(Kb + (size_t)(key0 + r)*64 + c8,      &Ks[0][(it*256 + wave*64)*8]);
            gl2lds16(Kb + (size_t)(key0 + r)*64 + 32 + c8, &Ks[1][(it*256 + wave*64)*8]);
        }
        // stage V^T tile: four [64][32] key-quarters, source-chunk swizzled
        {
            int r = tid >> 2;
            int c8 = (((tid & 3) ^ ((tid >> 3) & 3)) << 3);
#pragma unroll
            for (int qr = 0; qr < 4; ++qr)
                gl2lds16(Vb + (size_t)r*SEQ + key0 + qr*32 + c8, &Vs[qr][wave*64*8]);
        }
        // mask (global -> regs, overlaps the barrier drain)
        int4 mv[8];
#pragma unroll
        for (int nj = 0; nj < 8; ++nj)
            mv[nj] = *(const int4*)(mbase + key0 + nj*16 + quad*4);
        __syncthreads();   // staging drained

        // ---- QK^T: S^T tiles
        f32x4 st[2][8];
#pragma unroll
        for (int nj = 0; nj < 8; ++nj) {
            short8 k0 = *(const short8*)&Ks[0][(nj*16 + m16)*32 + koff];
            short8 k1 = *(const short8*)&Ks[1][(nj*16 + m16)*32 + koff];
#pragma unroll
            for (int qg = 0; qg < 2; ++qg) {
                f32x4 c = (f32x4){0.f,0.f,0.f,0.f};
                c = __builtin_amdgcn_mfma_f32_16x16x32_bf16(k0, qf[qg][0], c, 0, 0, 0);
                c = __builtin_amdgcn_mfma_f32_16x16x32_bf16(k1, qf[qg][1], c, 0, 0, 0);
                st[qg][nj] = c;
            }
        }

        // ---- online softmax per q-group (scores for q=m16 live in-lane)
        short4_t pb[2][8];
#pragma unroll
        for (int qg = 0; qg < 2; ++qg) {
            float s[8][4];
            float mx = -1e30f;
#pragma unroll
            for (int nj = 0; nj < 8; ++nj) {
                s[nj][0] = mv[nj].x ? st[qg][nj][0] : -1e9f;
                s[nj][1] = mv[nj].y ? st[qg][nj][1] : -1e9f;
                s[nj][2] = mv[nj].z ? st[qg][nj][2] : -1e9f;
                s[nj][3] = mv[nj].w ? st[qg][nj][3] : -1e9f;
                mx = fmaxf(mx, fmaxf(fmaxf(s[nj][0], s[nj][1]), fmaxf(s[nj][2], s[nj][3])));
            }
            mx = fmaxf(mx, __shfl_xor(mx, 16, 64));
            mx = fmaxf(mx, __shfl_xor(mx, 32, 64));
            float mnew = fmaxf(mrun[qg], mx);
            float alpha = __expf(mrun[qg] - mnew);
            float rs = 0.f;
#pragma unroll
            for (int nj = 0; nj < 8; ++nj) {
                float p0 = __expf(s[nj][0] - mnew);
                float p1 = __expf(s[nj][1] - mnew);
                float p2 = __expf(s[nj][2] - mnew);
                float p3 = __expf(s[nj][3] - mnew);
                rs += (p0 + p1) + (p2 + p3);
                pb[qg][nj] = (short4_t){(short)f2b(p0), (short)f2b(p1),
                                        (short)f2b(p2), (short)f2b(p3)};
            }
            rs += __shfl_xor(rs, 16, 64);
            rs += __shfl_xor(rs, 32, 64);
            mrun[qg] = mnew;
            lrun[qg] = lrun[qg] * alpha + rs;
#pragma unroll
            for (int dj = 0; dj < 4; ++dj) {
                accO[qg][dj][0] *= alpha; accO[qg][dj][1] *= alpha;
                accO[qg][dj][2] *= alpha; accO[qg][dj][3] *= alpha;
            }
        }

        // ---- PV: O^T += V^T·P^T, V frag shared across both q-groups
#pragma unroll
        for (int nj = 0; nj < 8; ++nj) {
            const int chx = (((nj & 1) << 1) | vch) ^ fsw;   // swizzled chunk
#pragma unroll
            for (int dj = 0; dj < 4; ++dj) {
                short4_t vf = *(const short4_t*)
                    &Vs[nj >> 1][(dj*16 + m16)*32 + chx*8 + vsub];
                accO[0][dj] = MFMA_K16(vf, pb[0][nj], accO[0][dj]);
                accO[1][dj] = MFMA_K16(vf, pb[1][nj], accO[1][dj]);
            }
        }
    }

#pragma unroll
    for (int qg = 0; qg < 2; ++qg) {
        float rl = 1.0f / lrun[qg];
#pragma unroll
        for (int dj = 0; dj < 4; ++dj) {
            short4_t o;
            o[0] = (short)f2b(accO[qg][dj][0] * rl);
            o[1] = (short)f2b(accO[qg][dj][1] * rl);
            o[2] = (short)f2b(accO[qg][dj][2] * rl);
            o[3] = (short)f2b(accO[qg][dj][3] * rl);
            *(short4_t*)&O[(size_t)(b*SEQ + qbase + qg*16 + m16)*D_EMBED
                           + h*HEAD_DIM + dj*16 + quad*4] = o;
        }
    }
}

// ---------------------------------------------------------------------------
// y = LayerNorm(A + B)*g + be -> fp32 Yf (and bf16 Yb if non-null)
// ---------------------------------------------------------------------------
__global__ __launch_bounds__(256) void ln_res(
    const float* __restrict__ A, const float* __restrict__ Bv,
    const float* __restrict__ g, const float* __restrict__ be,
    float* __restrict__ Yf, unsigned short* __restrict__ Yb)
{
    const int wave = threadIdx.x >> 6, lane = threadIdx.x & 63;
    const int row = blockIdx.x * 4 + wave;
    const float* ap = A  + (size_t)row*512 + lane*8;
    const float* bp = Bv + (size_t)row*512 + lane*8;
    float v[8]; float s = 0.f;
#pragma unroll
    for (int j = 0; j < 8; j++) { v[j] = ap[j] + bp[j]; s += v[j]; }
#pragma unroll
    for (int off = 32; off >= 1; off >>= 1) s += __shfl_xor(s, off, 64);
    float mu = s * (1.f/512.f);
    float q = 0.f;
#pragma unroll
    for (int j = 0; j < 8; j++) { v[j] -= mu; q += v[j]*v[j]; }
#pragma unroll
    for (int off = 32; off >= 1; off >>= 1) q += __shfl_xor(q, off, 64);
    float rstd = rsqrtf(q * (1.f/512.f) + 1e-5f);
#pragma unroll
    for (int j = 0; j < 8; j++) {
        float y = v[j]*rstd*g[lane*8+j] + be[lane*8+j];
        if (Yf) Yf[(size_t)row*512 + lane*8 + j] = y;
        if (Yb) Yb[(size_t)row*512 + lane*8 + j] = f2b(y);
    }
}

__global__ __launch_bounds__(256) void cvt_f32_bf16(
    const float* __restrict__ X, unsigned short* __restrict__ Y, int n)
{
    int idx = (blockIdx.x * 256 + threadIdx.x) * 4;
    if (idx < n) {
        float4 v = *(const float4*)(X + idx);
        Y[idx+0] = f2b(v.x); Y[idx+1] = f2b(v.y);
        Y[idx+2] = f2b(v.z); Y[idx+3] = f2b(v.w);
    }
}

// W[K][N] fp32 -> WT[N][K] bf16. block (32,8), grid (N/32, K/32)
__global__ void transpose_w(const float* __restrict__ W, unsigned short* __restrict__ WT,
                            int K, int N)
{
    __shared__ float t[32][33];
    int n0 = blockIdx.x*32, k0 = blockIdx.y*32;
    int x = threadIdx.x, y = threadIdx.y;
#pragma unroll
    for (int yy = y; yy < 32; yy += 8) t[yy][x] = W[(size_t)(k0+yy)*N + n0 + x];
    __syncthreads();
#pragma unroll
    for (int yy = y; yy < 32; yy += 8) WT[(size_t)(n0+yy)*K + k0 + x] = f2b(t[x][yy]);
}

__global__ void concat3(const float* __restrict__ a, const float* __restrict__ b,
                        const float* __restrict__ c, float* __restrict__ o)
{
    int i = blockIdx.x*256 + threadIdx.x;  // 1536 total
    o[i] = (i < 512) ? a[i] : ((i < 1024) ? b[i-512] : c[i-1024]);
}

extern "C" void kernel_launch(void* const* d_in, const int* in_sizes, int n_in,
                              void* d_out, int out_size, void* d_ws, size_t ws_size,
                              hipStream_t stream)
{
    const float* x    = (const float*)d_in[0];
    const int*   mask = (const int*)  d_in[1];
    const float* Wq = (const float*)d_in[2];  const float* bq = (const float*)d_in[3];
    const float* Wk = (const float*)d_in[4];  const float* bk = (const float*)d_in[5];
    const float* Wv = (const float*)d_in[6];  const float* bv = (const float*)d_in[7];
    const float* Wo = (const float*)d_in[8];  const float* bo = (const float*)d_in[9];
    const float* ln1g = (const float*)d_in[10]; const float* ln1b = (const float*)d_in[11];
    const float* ln2g = (const float*)d_in[12]; const float* ln2b = (const float*)d_in[13];
    const float* W1 = (const float*)d_in[14]; const float* b1 = (const float*)d_in[15];
    const float* W2 = (const float*)d_in[16]; const float* b2 = (const float*)d_in[17];
    float* out = (float*)d_out;

    char* ws = (char*)d_ws;
    const size_t MB = 1024*1024;
    // liveness-planned map (peak 79 MB):
    unsigned short* xb    = (unsigned short*)(ws + 0);           // 0..8, dead after QKV GEMM
    unsigned short* WqkvT = (unsigned short*)(ws + 8*MB);        // 8..9.5
    unsigned short* W1T   = (unsigned short*)(ws + 10*MB);       // 10..12
    unsigned short* W2T   = (unsigned short*)(ws + 12*MB);       // 12..14
    unsigned short* WoT   = (unsigned short*)(ws + 14*MB);       // 14..14.5
    float*          bqkv  = (float*)(ws + 14*MB + 512*1024);     // 6 KB
    unsigned short* QKVb  = (unsigned short*)(ws + 15*MB);       // 15..39, dead after repack
    unsigned short* Qp    = (unsigned short*)(ws + 39*MB);       // 39..47
    unsigned short* Kp    = (unsigned short*)(ws + 47*MB);       // 47..55
    unsigned short* Vp    = (unsigned short*)(ws + 55*MB);       // 55..63
    unsigned short* ctx   = (unsigned short*)(ws + 63*MB);       // 63..71
    float*          atf   = (float*)(ws + 15*MB);                // 15..31, overlays dead QKVb
    float*          hf    = (float*)(ws + 31*MB);                // 31..47, overlays dead QKVb/Qp
    unsigned short* hb    = (unsigned short*)(ws + 0);           // 0..8, overlays dead xb
    unsigned short* Gb    = (unsigned short*)(ws + 47*MB);       // 47..79, overlays dead Kp/Vp/ctx
    float*          ff    = (float*)(ws + 15*MB);                // 15..31, overlays dead atf

    dim3 tb(32, 8);
    cvt_f32_bf16<<<4096, 256, 0, stream>>>(x, xb, M_ROWS*D_EMBED);
    transpose_w<<<dim3(16,16), tb, 0, stream>>>(Wq, WqkvT,            512, 512);
    transpose_w<<<dim3(16,16), tb, 0, stream>>>(Wk, WqkvT + 512*512,  512, 512);
    transpose_w<<<dim3(16,16), tb, 0, stream>>>(Wv, WqkvT + 1024*512, 512, 512);
    transpose_w<<<dim3(16,16), tb, 0, stream>>>(Wo, WoT, 512, 512);
    transpose_w<<<dim3(64,16), tb, 0, stream>>>(W1, W1T, 512, 2048);
    transpose_w<<<dim3(16,64), tb, 0, stream>>>(W2, W2T, 2048, 512);
    concat3<<<6, 256, 0, stream>>>(bq, bk, bv, bqkv);

    // fused QKV projection, Q pre-scaled by 1/8
    gemm_bt<0><<<dim3(12,64), 256, 0, stream>>>(xb, WqkvT, bqkv, QKVb, M_ROWS, 1536, 512, 512);

    repack_qk<<<dim3(SEQ/64, 16), 256, 0, stream>>>(QKVb, Qp, Kp);
    transpose_v<<<dim3(SEQ/32, 2, 16), tb, 0, stream>>>(QKVb, Vp);
    flash_attn<<<dim3(SEQ/128, 16), 256, 0, stream>>>(Qp, Kp, Vp, mask, ctx);

    gemm_bt64<1><<<dim3(4,128), 256, 0, stream>>>(ctx, WoT, bo, atf, M_ROWS, 512, 512, 0);
    ln_res<<<M_ROWS/4, 256, 0, stream>>>(x, atf, ln1g, ln1b, hf, hb);

    gemm_bt<2><<<dim3(16,64), 256, 0, stream>>>(hb, W1T, b1, Gb, M_ROWS, D_FF, 512, 0);
    gemm_bt64<1><<<dim3(4,128), 256, 0, stream>>>(Gb, W2T, b2, ff, M_ROWS, 512, D_FF, 0);
    ln_res<<<M_ROWS/4, 256, 0, stream>>>(hf, ff, ln2g, ln2b, out, (unsigned short*)nullptr);
}

// Round 7
// 436.218 us; speedup vs baseline: 2.3001x; 1.1452x over previous
//
#include <hip/hip_runtime.h>
#include <hip/hip_bf16.h>
#include <math.h>

#define D_EMBED 512
#define NUM_HEADS 8
#define HEAD_DIM 64
#define D_FF 2048
#define BATCH 2
#define SEQ 4096
#define M_ROWS (BATCH*SEQ)   // 8192
// 0.125 * log2(e): folds softmax's exp->exp2 conversion into the Q projection
#define QSCALE 0.18033688011112042f

typedef __attribute__((ext_vector_type(8))) short short8;
typedef __attribute__((ext_vector_type(4))) short short4_t;
typedef __attribute__((ext_vector_type(4))) float f32x4;

// Device pass has one of these (R2/R4/R5/R6 proved the K16 path is taken and
// correct). Host pass may have neither -> benign parse-only stub.
#if __has_builtin(__builtin_amdgcn_mfma_f32_16x16x16bf16_1k)
#define MFMA_K16(a,b,c) __builtin_amdgcn_mfma_f32_16x16x16bf16_1k(a,b,c,0,0,0)
#elif __has_builtin(__builtin_amdgcn_mfma_f32_16x16x16_bf16)
#define MFMA_K16(a,b,c) __builtin_amdgcn_mfma_f32_16x16x16_bf16(a,b,c,0,0,0)
#else
#define MFMA_K16(a,b,c) (c)   // host-pass parse stub
#endif

#if __has_builtin(__builtin_amdgcn_exp2f)
#define EXP2(x) __builtin_amdgcn_exp2f(x)
#else
#define EXP2(x) exp2f(x)
#endif

__device__ inline unsigned short f2b(float f) {
    union { float f; unsigned u; } v; v.f = f;
    unsigned r = v.u + 0x7fffu + ((v.u >> 16) & 1u);
    return (unsigned short)(r >> 16);
}

// pack 4 fp32 -> 4 bf16 (RNE) using packed cvt where available
__device__ inline short4_t pk4(float p0, float p1, float p2, float p3) {
    union { __hip_bfloat162 h2[2]; short4_t s4; } u;
    u.h2[0] = __float22bfloat162_rn(make_float2(p0, p1));
    u.h2[1] = __float22bfloat162_rn(make_float2(p2, p3));
    return u.s4;
}

__device__ inline void gl2lds16(const void* g, void* l) {
    __builtin_amdgcn_global_load_lds(
        (const __attribute__((address_space(1))) unsigned int*)g,
        (__attribute__((address_space(3))) unsigned int*)l, 16, 0, 0);
}

// XOR swizzle: 64B LDS rows, 4 chunks of 16B. chunk' = chunk ^ ((row>>1)&3).
// Staged on the SOURCE side (within-cacheline permutation), undone on read.

// ---------------------------------------------------------------------------
// GEMM 128x128: C[M][N] = A[M][K](bf16) * BT[N][K](bf16)^T + bias
// EPI 0: bf16; EPI 1: fp32; EPI 2: GELU->bf16. Cols < scale_cols get *QSCALE.
// ---------------------------------------------------------------------------
template<int EPI>
__global__ __launch_bounds__(256) void gemm_bt(
    const unsigned short* __restrict__ A, const unsigned short* __restrict__ BT,
    const float* __restrict__ bias, void* __restrict__ Cout,
    int M, int N, int K, int scale_cols)
{
    __shared__ __align__(16) unsigned short As[128*32];
    __shared__ __align__(16) unsigned short Bs[128*32];
    const int tid  = threadIdx.x;
    const int wave = tid >> 6, lane = tid & 63;
    const int wy = wave >> 1, wx = wave & 1;
    const int quad = lane >> 4, m16 = lane & 15;
    const int row0 = blockIdx.y * 128, n0 = blockIdx.x * 128;
    const int rdoff = (quad ^ ((m16 >> 1) & 3)) * 8;   // swizzled read chunk

    f32x4 acc[4][4];
#pragma unroll
    for (int i = 0; i < 4; i++)
#pragma unroll
        for (int j = 0; j < 4; j++) acc[i][j] = (f32x4){0.f,0.f,0.f,0.f};

    const int kIters = K >> 5;
    for (int kt = 0; kt < kIters; ++kt) {
        const int k0 = kt << 5;
#pragma unroll
        for (int it = 0; it < 2; ++it) {
            int g  = it*256 + tid;
            int r  = g >> 2;
            int c8 = (((g & 3) ^ ((g >> 3) & 3)) << 3);   // swizzled source chunk
            gl2lds16(A  + (size_t)(row0 + r)*K + k0 + c8, &As[(size_t)(it*256 + wave*64)*8]);
            gl2lds16(BT + (size_t)(n0  + r)*K + k0 + c8, &Bs[(size_t)(it*256 + wave*64)*8]);
        }
        __syncthreads();
        short8 a[4], b[4];
#pragma unroll
        for (int i = 0; i < 4; i++) a[i] = *(const short8*)&As[(wy*64 + i*16 + m16)*32 + rdoff];
#pragma unroll
        for (int j = 0; j < 4; j++) b[j] = *(const short8*)&Bs[(wx*64 + j*16 + m16)*32 + rdoff];
#pragma unroll
        for (int i = 0; i < 4; i++)
#pragma unroll
            for (int j = 0; j < 4; j++)
                acc[i][j] = __builtin_amdgcn_mfma_f32_16x16x32_bf16(a[i], b[j], acc[i][j], 0, 0, 0);
        __syncthreads();
    }

#pragma unroll
    for (int j = 0; j < 4; j++) {
        int col = n0 + wx*64 + j*16 + m16;
        float bj = bias[col];
        float sc = (col < scale_cols) ? QSCALE : 1.0f;
#pragma unroll
        for (int i = 0; i < 4; i++) {
            int rbase = row0 + wy*64 + i*16 + quad*4;
#pragma unroll
            for (int r = 0; r < 4; r++) {
                float v = (acc[i][j][r] + bj) * sc;
                size_t idx = (size_t)(rbase + r)*N + col;
                if (EPI == 0) {
                    ((unsigned short*)Cout)[idx] = f2b(v);
                } else if (EPI == 1) {
                    ((float*)Cout)[idx] = v;
                } else {
                    float gv = 0.5f * v * (1.0f + erff(v * 0.70710678118654752f));
                    ((unsigned short*)Cout)[idx] = f2b(gv);
                }
            }
        }
    }
}

// ---------------------------------------------------------------------------
// GEMM 64x128 tile (for N=512 matmuls: doubles grid to 512 blocks = 2/CU)
// ---------------------------------------------------------------------------
template<int EPI>
__global__ __launch_bounds__(256) void gemm_bt64(
    const unsigned short* __restrict__ A, const unsigned short* __restrict__ BT,
    const float* __restrict__ bias, void* __restrict__ Cout,
    int M, int N, int K, int scale_cols)
{
    __shared__ __align__(16) unsigned short As[64*32];
    __shared__ __align__(16) unsigned short Bs[128*32];
    const int tid  = threadIdx.x;
    const int wave = tid >> 6, lane = tid & 63;
    const int wy = wave >> 1, wx = wave & 1;
    const int quad = lane >> 4, m16 = lane & 15;
    const int row0 = blockIdx.y * 64, n0 = blockIdx.x * 128;
    const int rdoff = (quad ^ ((m16 >> 1) & 3)) * 8;

    f32x4 acc[2][4];
#pragma unroll
    for (int i = 0; i < 2; i++)
#pragma unroll
        for (int j = 0; j < 4; j++) acc[i][j] = (f32x4){0.f,0.f,0.f,0.f};

    const int kIters = K >> 5;
    for (int kt = 0; kt < kIters; ++kt) {
        const int k0 = kt << 5;
        {
            int r = tid >> 2;
            int c8 = (((tid & 3) ^ ((tid >> 3) & 3)) << 3);
            gl2lds16(A + (size_t)(row0 + r)*K + k0 + c8, &As[(size_t)(wave*64)*8]);
        }
#pragma unroll
        for (int it = 0; it < 2; ++it) {
            int g  = it*256 + tid;
            int r  = g >> 2;
            int c8 = (((g & 3) ^ ((g >> 3) & 3)) << 3);
            gl2lds16(BT + (size_t)(n0 + r)*K + k0 + c8, &Bs[(size_t)(it*256 + wave*64)*8]);
        }
        __syncthreads();
        short8 a[2], b[4];
#pragma unroll
        for (int i = 0; i < 2; i++) a[i] = *(const short8*)&As[(wy*32 + i*16 + m16)*32 + rdoff];
#pragma unroll
        for (int j = 0; j < 4; j++) b[j] = *(const short8*)&Bs[(wx*64 + j*16 + m16)*32 + rdoff];
#pragma unroll
        for (int i = 0; i < 2; i++)
#pragma unroll
            for (int j = 0; j < 4; j++)
                acc[i][j] = __builtin_amdgcn_mfma_f32_16x16x32_bf16(a[i], b[j], acc[i][j], 0, 0, 0);
        __syncthreads();
    }

#pragma unroll
    for (int j = 0; j < 4; j++) {
        int col = n0 + wx*64 + j*16 + m16;
        float bj = bias[col];
        float sc = (col < scale_cols) ? QSCALE : 1.0f;
#pragma unroll
        for (int i = 0; i < 2; i++) {
            int rbase = row0 + wy*32 + i*16 + quad*4;
#pragma unroll
            for (int r = 0; r < 4; r++) {
                float v = (acc[i][j][r] + bj) * sc;
                size_t idx = (size_t)(rbase + r)*N + col;
                if (EPI == 0) {
                    ((unsigned short*)Cout)[idx] = f2b(v);
                } else if (EPI == 1) {
                    ((float*)Cout)[idx] = v;
                } else {
                    float gv = 0.5f * v * (1.0f + erff(v * 0.70710678118654752f));
                    ((unsigned short*)Cout)[idx] = f2b(gv);
                }
            }
        }
    }
}

// ---------------------------------------------------------------------------
// Repack Q,K from fused QKV [8192][1536] into per-head [bh][SEQ][64].
// ---------------------------------------------------------------------------
__global__ __launch_bounds__(256) void repack_qk(
    const unsigned short* __restrict__ QKV,
    unsigned short* __restrict__ Qp, unsigned short* __restrict__ Kp)
{
    const int bh = blockIdx.y, b = bh >> 3, h = bh & 7;
    const int l0 = blockIdx.x * 64;
    const int t = threadIdx.x;
    const int row = t >> 2, c = (t & 3) * 16;
    const unsigned short* src = QKV + (size_t)(b*SEQ + l0 + row)*1536 + h*64 + c;
    const size_t dst = ((size_t)bh*SEQ + l0 + row)*64 + c;
    *(short8*)&Qp[dst]   = *(const short8*)(src);
    *(short8*)&Qp[dst+8] = *(const short8*)(src + 8);
    *(short8*)&Kp[dst]   = *(const short8*)(src + 512);
    *(short8*)&Kp[dst+8] = *(const short8*)(src + 520);
}

// ---------------------------------------------------------------------------
// V (cols 1024..1535 of QKV) -> VT [bh][64 d][SEQ]. grid (SEQ/32, 2, 16)
// ---------------------------------------------------------------------------
__global__ void transpose_v(const unsigned short* __restrict__ QKV, unsigned short* __restrict__ VT)
{
    __shared__ unsigned short t[32][33];
    int bh = blockIdx.z, b = bh >> 3, h = bh & 7;
    int l0 = blockIdx.x*32, d0 = blockIdx.y*32;
    int x = threadIdx.x, y = threadIdx.y;
#pragma unroll
    for (int yy = y; yy < 32; yy += 8)
        t[yy][x] = QKV[(size_t)(b*SEQ + l0+yy)*1536 + 1024 + h*64 + d0 + x];
    __syncthreads();
#pragma unroll
    for (int yy = y; yy < 32; yy += 8)
        VT[((size_t)bh*64 + d0+yy)*SEQ + l0 + x] = t[x][yy];
}

// per-128-key-tile all-ones flags: flags[b*32+kt] = 1 iff mask[b][kt*128..+128)
// all nonzero. 64 flags total.
__global__ void mask_flags_k(const int* __restrict__ mask, int* __restrict__ flags)
{
    int t = threadIdx.x;   // 64 threads
    const int* m = mask + t*128;
    int all = 1;
    for (int i = 0; i < 128; i += 4) {
        int4 v = *(const int4*)(m + i);
        all &= (v.x && v.y && v.z && v.w) ? 1 : 0;
    }
    flags[t] = all;
}

// ---------------------------------------------------------------------------
// Flash attention. grid (SEQ/64, B*H), 256 threads; each wave owns 16 q rows.
// K-tile = 128 keys staged to LDS (shared by all 4 waves), XOR bank swizzle.
// Softmax in exp2 domain (QSCALE folds in log2e); packed bf16 cvt; mask
// skipped entirely on all-ones tiles (precomputed flags).
// ---------------------------------------------------------------------------
__global__ __launch_bounds__(256) void flash_attn(
    const unsigned short* __restrict__ Qp, const unsigned short* __restrict__ Kp,
    const unsigned short* __restrict__ VT, const int* __restrict__ mask,
    const int* __restrict__ flags, unsigned short* __restrict__ O)
{
    __shared__ __align__(16) unsigned short Ks[2][128*32];
    __shared__ __align__(16) unsigned short Vs[4][64*32];
    const int tid = threadIdx.x, wave = tid >> 6, lane = tid & 63;
    const int quad = lane >> 4, m16 = lane & 15;
    const int bh = blockIdx.y, b = bh >> 3, h = bh & 7;
    const int qbase = blockIdx.x * 64 + wave * 16;
    const int fsw = (m16 >> 1) & 3;                  // row-derived swizzle key
    const int koff = (quad ^ fsw) * 8;               // Ks b128 read offset
    const int vch  = (quad >> 1);                    // Vs chunk base
    const int vsub = (quad & 1) * 4;                 // Vs 8B sub-offset

    const unsigned short* Qb = Qp + (size_t)bh*SEQ*64;
    const unsigned short* Kb = Kp + (size_t)bh*SEQ*64;
    const unsigned short* Vb = VT + (size_t)bh*64*SEQ;
    const int* mbase = mask + b*SEQ;
    const int* fbase = flags + b*(SEQ/128);

    short8 qf[2];
    {
        const unsigned short* qp = Qb + (size_t)(qbase + m16)*64 + quad*8;
        qf[0] = *(const short8*)qp;
        qf[1] = *(const short8*)(qp + 32);
    }

    f32x4 accO[4];
#pragma unroll
    for (int dj = 0; dj < 4; dj++) accO[dj] = (f32x4){0.f,0.f,0.f,0.f};
    float mrun = -1e30f, lrun = 0.f;

    for (int kt = 0; kt < SEQ/128; ++kt) {
        const int key0 = kt * 128;
        const int allones = fbase[kt];
        __syncthreads();   // all waves done reading previous tile
        // stage K tile: two [128][32] halves, source-chunk swizzled
#pragma unroll
        for (int it = 0; it < 2; ++it) {
            int g = it*256 + tid;
            int r = g >> 2;
            int c8 = (((g & 3) ^ ((g >> 3) & 3)) << 3);
            gl2lds16(Kb + (size_t)(key0 + r)*64 + c8,      &Ks[0][(it*256 + wave*64)*8]);
            gl2lds16(Kb + (size_t)(key0 + r)*64 + 32 + c8, &Ks[1][(it*256 + wave*64)*8]);
        }
        // stage V^T tile: four [64][32] key-quarters, source-chunk swizzled
        {
            int r = tid >> 2;
            int c8 = (((tid & 3) ^ ((tid >> 3) & 3)) << 3);
#pragma unroll
            for (int qr = 0; qr < 4; ++qr)
                gl2lds16(Vb + (size_t)r*SEQ + key0 + qr*32 + c8, &Vs[qr][wave*64*8]);
        }
        __syncthreads();   // staging drained

        // ---- QK^T: S^T tiles (scores already in log2 domain via QSCALE)
        f32x4 st[8];
#pragma unroll
        for (int nj = 0; nj < 8; ++nj) {
            short8 k0 = *(const short8*)&Ks[0][(nj*16 + m16)*32 + koff];
            short8 k1 = *(const short8*)&Ks[1][(nj*16 + m16)*32 + koff];
            f32x4 c = (f32x4){0.f,0.f,0.f,0.f};
            c = __builtin_amdgcn_mfma_f32_16x16x32_bf16(k0, qf[0], c, 0, 0, 0);
            c = __builtin_amdgcn_mfma_f32_16x16x32_bf16(k1, qf[1], c, 0, 0, 0);
            st[nj] = c;
        }

        // ---- mask (slow path only; all-ones tiles skip entirely)
        if (!allones) {
#pragma unroll
            for (int nj = 0; nj < 8; ++nj) {
                int4 mv = *(const int4*)(mbase + key0 + nj*16 + quad*4);
                st[nj][0] = mv.x ? st[nj][0] : -1e9f;
                st[nj][1] = mv.y ? st[nj][1] : -1e9f;
                st[nj][2] = mv.z ? st[nj][2] : -1e9f;
                st[nj][3] = mv.w ? st[nj][3] : -1e9f;
            }
        }

        // ---- online softmax (exp2 domain; per-lane scores belong to q=m16)
        float mx = -1e30f;
#pragma unroll
        for (int nj = 0; nj < 8; ++nj)
            mx = fmaxf(mx, fmaxf(fmaxf(st[nj][0], st[nj][1]),
                                 fmaxf(st[nj][2], st[nj][3])));
        mx = fmaxf(mx, __shfl_xor(mx, 16, 64));
        mx = fmaxf(mx, __shfl_xor(mx, 32, 64));
        float mnew = fmaxf(mrun, mx);
        float alpha = EXP2(mrun - mnew);

        short4_t pb[8];
        float rs = 0.f;
#pragma unroll
        for (int nj = 0; nj < 8; ++nj) {
            float p0 = EXP2(st[nj][0] - mnew);
            float p1 = EXP2(st[nj][1] - mnew);
            float p2 = EXP2(st[nj][2] - mnew);
            float p3 = EXP2(st[nj][3] - mnew);
            rs += (p0 + p1) + (p2 + p3);
            pb[nj] = pk4(p0, p1, p2, p3);
        }
        rs += __shfl_xor(rs, 16, 64);
        rs += __shfl_xor(rs, 32, 64);
        mrun = mnew;
        lrun = lrun * alpha + rs;
#pragma unroll
        for (int dj = 0; dj < 4; ++dj) {
            accO[dj][0] *= alpha; accO[dj][1] *= alpha;
            accO[dj][2] *= alpha; accO[dj][3] *= alpha;
        }

        // ---- PV: O^T += V^T·P^T
#pragma unroll
        for (int nj = 0; nj < 8; ++nj) {
            const int chx = (((nj & 1) << 1) | vch) ^ fsw;   // swizzled chunk
#pragma unroll
            for (int dj = 0; dj < 4; ++dj) {
                short4_t vf = *(const short4_t*)
                    &Vs[nj >> 1][(dj*16 + m16)*32 + chx*8 + vsub];
                accO[dj] = MFMA_K16(vf, pb[nj], accO[dj]);
            }
        }
    }

    float rl = 1.0f / lrun;
#pragma unroll
    for (int dj = 0; dj < 4; ++dj) {
        short4_t o = pk4(accO[dj][0]*rl, accO[dj][1]*rl,
                         accO[dj][2]*rl, accO[dj][3]*rl);
        *(short4_t*)&O[(size_t)(b*SEQ + qbase + m16)*D_EMBED
                       + h*HEAD_DIM + dj*16 + quad*4] = o;
    }
}

// ---------------------------------------------------------------------------
// y = LayerNorm(A + B)*g + be -> fp32 Yf (and bf16 Yb if non-null)
// ---------------------------------------------------------------------------
__global__ __launch_bounds__(256) void ln_res(
    const float* __restrict__ A, const float* __restrict__ Bv,
    const float* __restrict__ g, const float* __restrict__ be,
    float* __restrict__ Yf, unsigned short* __restrict__ Yb)
{
    const int wave = threadIdx.x >> 6, lane = threadIdx.x & 63;
    const int row = blockIdx.x * 4 + wave;
    const float* ap = A  + (size_t)row*512 + lane*8;
    const float* bp = Bv + (size_t)row*512 + lane*8;
    float v[8]; float s = 0.f;
#pragma unroll
    for (int j = 0; j < 8; j++) { v[j] = ap[j] + bp[j]; s += v[j]; }
#pragma unroll
    for (int off = 32; off >= 1; off >>= 1) s += __shfl_xor(s, off, 64);
    float mu = s * (1.f/512.f);
    float q = 0.f;
#pragma unroll
    for (int j = 0; j < 8; j++) { v[j] -= mu; q += v[j]*v[j]; }
#pragma unroll
    for (int off = 32; off >= 1; off >>= 1) q += __shfl_xor(q, off, 64);
    float rstd = rsqrtf(q * (1.f/512.f) + 1e-5f);
#pragma unroll
    for (int j = 0; j < 8; j++) {
        float y = v[j]*rstd*g[lane*8+j] + be[lane*8+j];
        if (Yf) Yf[(size_t)row*512 + lane*8 + j] = y;
        if (Yb) Yb[(size_t)row*512 + lane*8 + j] = f2b(y);
    }
}

__global__ __launch_bounds__(256) void cvt_f32_bf16(
    const float* __restrict__ X, unsigned short* __restrict__ Y, int n)
{
    int idx = (blockIdx.x * 256 + threadIdx.x) * 4;
    if (idx < n) {
        float4 v = *(const float4*)(X + idx);
        Y[idx+0] = f2b(v.x); Y[idx+1] = f2b(v.y);
        Y[idx+2] = f2b(v.z); Y[idx+3] = f2b(v.w);
    }
}

// W[K][N] fp32 -> WT[N][K] bf16. block (32,8), grid (N/32, K/32)
__global__ void transpose_w(const float* __restrict__ W, unsigned short* __restrict__ WT,
                            int K, int N)
{
    __shared__ float t[32][33];
    int n0 = blockIdx.x*32, k0 = blockIdx.y*32;
    int x = threadIdx.x, y = threadIdx.y;
#pragma unroll
    for (int yy = y; yy < 32; yy += 8) t[yy][x] = W[(size_t)(k0+yy)*N + n0 + x];
    __syncthreads();
#pragma unroll
    for (int yy = y; yy < 32; yy += 8) WT[(size_t)(n0+yy)*K + k0 + x] = f2b(t[x][yy]);
}

__global__ void concat3(const float* __restrict__ a, const float* __restrict__ b,
                        const float* __restrict__ c, float* __restrict__ o)
{
    int i = blockIdx.x*256 + threadIdx.x;  // 1536 total
    o[i] = (i < 512) ? a[i] : ((i < 1024) ? b[i-512] : c[i-1024]);
}

extern "C" void kernel_launch(void* const* d_in, const int* in_sizes, int n_in,
                              void* d_out, int out_size, void* d_ws, size_t ws_size,
                              hipStream_t stream)
{
    const float* x    = (const float*)d_in[0];
    const int*   mask = (const int*)  d_in[1];
    const float* Wq = (const float*)d_in[2];  const float* bq = (const float*)d_in[3];
    const float* Wk = (const float*)d_in[4];  const float* bk = (const float*)d_in[5];
    const float* Wv = (const float*)d_in[6];  const float* bv = (const float*)d_in[7];
    const float* Wo = (const float*)d_in[8];  const float* bo = (const float*)d_in[9];
    const float* ln1g = (const float*)d_in[10]; const float* ln1b = (const float*)d_in[11];
    const float* ln2g = (const float*)d_in[12]; const float* ln2b = (const float*)d_in[13];
    const float* W1 = (const float*)d_in[14]; const float* b1 = (const float*)d_in[15];
    const float* W2 = (const float*)d_in[16]; const float* b2 = (const float*)d_in[17];
    float* out = (float*)d_out;

    char* ws = (char*)d_ws;
    const size_t MB = 1024*1024;
    // liveness-planned map (peak 79 MB):
    unsigned short* xb    = (unsigned short*)(ws + 0);           // 0..8, dead after QKV GEMM
    unsigned short* WqkvT = (unsigned short*)(ws + 8*MB);        // 8..9.5
    unsigned short* W1T   = (unsigned short*)(ws + 10*MB);       // 10..12
    unsigned short* W2T   = (unsigned short*)(ws + 12*MB);       // 12..14
    unsigned short* WoT   = (unsigned short*)(ws + 14*MB);       // 14..14.5
    float*          bqkv  = (float*)(ws + 14*MB + 512*1024);     // 6 KB
    int*            mflag = (int*)(ws + 14*MB + 768*1024);       // 256 B
    unsigned short* QKVb  = (unsigned short*)(ws + 15*MB);       // 15..39, dead after repack
    unsigned short* Qp    = (unsigned short*)(ws + 39*MB);       // 39..47
    unsigned short* Kp    = (unsigned short*)(ws + 47*MB);       // 47..55
    unsigned short* Vp    = (unsigned short*)(ws + 55*MB);       // 55..63
    unsigned short* ctx   = (unsigned short*)(ws + 63*MB);       // 63..71
    float*          atf   = (float*)(ws + 15*MB);                // 15..31, overlays dead QKVb
    float*          hf    = (float*)(ws + 31*MB);                // 31..47, overlays dead QKVb/Qp
    unsigned short* hb    = (unsigned short*)(ws + 0);           // 0..8, overlays dead xb
    unsigned short* Gb    = (unsigned short*)(ws + 47*MB);       // 47..79, overlays dead Kp/Vp/ctx
    float*          ff    = (float*)(ws + 15*MB);                // 15..31, overlays dead atf

    dim3 tb(32, 8);
    cvt_f32_bf16<<<4096, 256, 0, stream>>>(x, xb, M_ROWS*D_EMBED);
    transpose_w<<<dim3(16,16), tb, 0, stream>>>(Wq, WqkvT,            512, 512);
    transpose_w<<<dim3(16,16), tb, 0, stream>>>(Wk, WqkvT + 512*512,  512, 512);
    transpose_w<<<dim3(16,16), tb, 0, stream>>>(Wv, WqkvT + 1024*512, 512, 512);
    transpose_w<<<dim3(16,16), tb, 0, stream>>>(Wo, WoT, 512, 512);
    transpose_w<<<dim3(64,16), tb, 0, stream>>>(W1, W1T, 512, 2048);
    transpose_w<<<dim3(16,64), tb, 0, stream>>>(W2, W2T, 2048, 512);
    concat3<<<6, 256, 0, stream>>>(bq, bk, bv, bqkv);
    mask_flags_k<<<1, 64, 0, stream>>>(mask, mflag);

    // fused QKV projection, Q pre-scaled by QSCALE (0.125*log2e)
    gemm_bt<0><<<dim3(12,64), 256, 0, stream>>>(xb, WqkvT, bqkv, QKVb, M_ROWS, 1536, 512, 512);

    repack_qk<<<dim3(SEQ/64, 16), 256, 0, stream>>>(QKVb, Qp, Kp);
    transpose_v<<<dim3(SEQ/32, 2, 16), tb, 0, stream>>>(QKVb, Vp);
    flash_attn<<<dim3(SEQ/64, 16), 256, 0, stream>>>(Qp, Kp, Vp, mask, mflag, ctx);

    gemm_bt64<1><<<dim3(4,128), 256, 0, stream>>>(ctx, WoT, bo, atf, M_ROWS, 512, 512, 0);
    ln_res<<<M_ROWS/4, 256, 0, stream>>>(x, atf, ln1g, ln1b, hf, hb);

    gemm_bt<2><<<dim3(16,64), 256, 0, stream>>>(hb, W1T, b1, Gb, M_ROWS, D_FF, 512, 0);
    gemm_bt64<1><<<dim3(4,128), 256, 0, stream>>>(Gb, W2T, b2, ff, M_ROWS, 512, D_FF, 0);
    ln_res<<<M_ROWS/4, 256, 0, stream>>>(hf, ff, ln2g, ln2b, out, (unsigned short*)nullptr);
}